// Round 1
// 545.598 us; speedup vs baseline: 1.1206x; 1.1206x over previous
//
#include <hip/hip_runtime.h>
#include <hip/hip_bf16.h>
#include <stdint.h>

typedef __hip_bfloat16 bf16;
typedef __bf16 bf16x8 __attribute__((ext_vector_type(8)));
typedef float f32x4 __attribute__((ext_vector_type(4)));

#define NB 1024
#define NM 4096
#define NZ 64
#define NH 8192

__device__ __forceinline__ float bf2f(bf16 x) { return __bfloat162float(x); }
__device__ __forceinline__ bf16 f2bf(float x) { return __float2bfloat16(x); }
__device__ __forceinline__ float sigf(float x) { return 1.f / (1.f + __expf(-x)); }

// fp32 x -> bf16 (4 elements/thread)
__global__ __launch_bounds__(256) void cvt_f32_bf16(const float* __restrict__ src,
                                                    bf16* __restrict__ dst, int n4) {
  const int i = blockIdx.x * 256 + threadIdx.x;
  if (i >= n4) return;
  const float4 v = ((const float4*)src)[i];
  bf16 o[4] = {f2bf(v.x), f2bf(v.y), f2bf(v.z), f2bf(v.w)};
  *(short4*)&dst[i * 4] = *(short4*)o;
}

__global__ void zero_f32(float* p, int n) {
  int i = blockIdx.x * blockDim.x + threadIdx.x;
  if (i < n) p[i] = 0.f;
}

// ---------------------------------------------------------------------------
// MFMA NT GEMM v2: C[r,c] = relu( sum_k A[r,k]*W[c,k] + bias[c] )
// A bf16 (pre-converted), W fp32 (converted in staging), bias fp32, C bf16.
// Tile 128x64, BK=64, 256 threads = 4 waves (2x2), wave -> 64x32 C sub-tile.
//  - grid 8x64 = 512 blocks = 2 blocks/CU (cross-block overlap of barrier drain)
//  - XCD-bijective block swizzle (512%8==0): XCD k owns col-panels 8k..8k+7 for
//    all row-tiles -> each W panel fetched by exactly one per-XCD L2
//  - A staged via global_load_lds width=16 (linear LDS dest, inverse-swizzled
//    global source per rule-21); W reg-staged fp32->bf16 with swizzled ds_write
//  - both LDS tiles XOR-swizzled: elem_off = row*64 + (ke ^ ((row&7)<<3))
//    -> frag ds_read_b128 drops from 16-way to 2-way (free) bank aliasing
// ---------------------------------------------------------------------------
__global__ __launch_bounds__(256) void gemm_nt(const bf16* __restrict__ A,
                                               const float* __restrict__ W,
                                               const float* __restrict__ bias,
                                               bf16* __restrict__ C,
                                               int K, int N) {
  __shared__ __attribute__((aligned(16))) bf16 smA[128 * 64];  // 16 KB
  __shared__ __attribute__((aligned(16))) bf16 smB[64 * 64];   // 8 KB
  const int tid  = threadIdx.x;
  const int lane = tid & 63;
  const int w    = tid >> 6;   // 0..3
  const int wr   = w >> 1;     // 0..1 : 64-row group
  const int wc   = w & 1;      // 0..1 : 32-col group

  // XCD-bijective swizzle (hw linear id: x fastest, gridDim.x == 8)
  const int lid  = blockIdx.y * 8 + blockIdx.x;   // 0..511
  const int wgid = (lid & 7) * 64 + (lid >> 3);   // per-XCD contiguous chunk
  const int row0 = (wgid & 7) * 128;
  const int col0 = (wgid >> 3) * 64;

  f32x4 acc[4][2];
#pragma unroll
  for (int i = 0; i < 4; i++)
#pragma unroll
    for (int j = 0; j < 2; j++) acc[i][j] = (f32x4){0.f, 0.f, 0.f, 0.f};

  // W staging map: thread -> smB row tid>>2, k elems [(tid&3)*16, +16)
  const int swr = tid >> 2;
  const int swk = (tid & 3) * 16;
  const float* wp = W + (size_t)(col0 + swr) * K + swk;
  const int swz = (swr & 7) << 3;   // element XOR for this row
  bf16* const wdst0 = &smB[swr * 64 + ((swk + 0) ^ swz)];
  bf16* const wdst1 = &smB[swr * 64 + ((swk + 8) ^ swz)];

  for (int k0 = 0; k0 < K; k0 += 64) {
    // W global->reg early (latency hidden across both barriers)
    const float4 wf0 = *(const float4*)(wp + k0);
    const float4 wf1 = *(const float4*)(wp + k0 + 4);
    const float4 wf2 = *(const float4*)(wp + k0 + 8);
    const float4 wf3 = *(const float4*)(wp + k0 + 12);
    __syncthreads();   // previous tile's LDS reads done

    // A -> LDS, linear dest chunk = q*256 + w*64 + lane (wave-uniform base +
    // lane*16); global source inverse-swizzled so swizzled reads see A[r][ke]
#pragma unroll
    for (int q = 0; q < 4; q++) {
      const int chunk = q * 256 + w * 64 + lane;
      const int r  = chunk >> 3;
      const int ke = ((chunk & 7) ^ (r & 7)) * 8;
      __builtin_amdgcn_global_load_lds(
          (__attribute__((address_space(1))) unsigned int*)(A + (size_t)(row0 + r) * K + (k0 + ke)),
          (__attribute__((address_space(3))) unsigned int*)(&smA[(q * 256 + w * 64) * 8]),
          16, 0, 0);
    }
    // W cvt -> swizzled LDS
    {
      bf16 t[16] = {f2bf(wf0.x), f2bf(wf0.y), f2bf(wf0.z), f2bf(wf0.w),
                    f2bf(wf1.x), f2bf(wf1.y), f2bf(wf1.z), f2bf(wf1.w),
                    f2bf(wf2.x), f2bf(wf2.y), f2bf(wf2.z), f2bf(wf2.w),
                    f2bf(wf3.x), f2bf(wf3.y), f2bf(wf3.z), f2bf(wf3.w)};
      *(bf16x8*)wdst0 = ((bf16x8*)t)[0];
      *(bf16x8*)wdst1 = ((bf16x8*)t)[1];
    }
    __syncthreads();   // compiler drains vmcnt(0)+lgkmcnt(0) here: tile visible

#pragma unroll
    for (int ks = 0; ks < 64; ks += 32) {
      const int kq = ks + (lane >> 4) * 8;   // frag: [m|n = lane&15][k = quad*8+j]
      bf16x8 af[4], bfr[2];
#pragma unroll
      for (int i = 0; i < 4; i++) {
        const int r = wr * 64 + i * 16 + (lane & 15);
        af[i] = *(const bf16x8*)&smA[r * 64 + (kq ^ ((r & 7) << 3))];
      }
#pragma unroll
      for (int j = 0; j < 2; j++) {
        const int r = wc * 32 + j * 16 + (lane & 15);
        bfr[j] = *(const bf16x8*)&smB[r * 64 + (kq ^ ((r & 7) << 3))];
      }
#pragma unroll
      for (int i = 0; i < 4; i++)
#pragma unroll
        for (int j = 0; j < 2; j++)
          acc[i][j] = __builtin_amdgcn_mfma_f32_16x16x32_bf16(af[i], bfr[j], acc[i][j], 0, 0, 0);
    }
  }

  // C/D layout: col = lane&15, row = (lane>>4)*4 + t   [m89-verified]
#pragma unroll
  for (int i = 0; i < 4; i++) {
#pragma unroll
    for (int j = 0; j < 2; j++) {
      const int cc = col0 + wc * 32 + j * 16 + (lane & 15);
      const float bs = bias[cc];
#pragma unroll
      for (int t = 0; t < 4; t++) {
        const int rr = row0 + wr * 64 + i * 16 + (lane >> 4) * 4 + t;
        float v = acc[i][j][t] + bs;
        v = v > 0.f ? v : 0.f;   // relu (both encoder layers)
        C[(size_t)rr * N + cc] = f2bf(v);
      }
    }
  }
}

// ---------------------------------------------------------------------------
// mu/logvar split-K: zpre[b, 0..63]=mu-dot, [64..127]=lv-dot (fp32 atomics).
// A = h2 bf16, weights fp32. grid (16 b-tiles, 16 k-chunks of 256), block 256.
// ---------------------------------------------------------------------------
__global__ __launch_bounds__(256) void mulv_splitk(const bf16* __restrict__ h2,
                                                   const float* __restrict__ muw,
                                                   const float* __restrict__ lvw,
                                                   float* __restrict__ zpre) {
  __shared__ float sA[32][64];    // [k][b]
  __shared__ float sW[32][128];   // [k][j]
  const int tid = threadIdx.x;
  const int b0 = blockIdx.x * 64;
  const int k0 = blockIdx.y * 256;
  const int tj = tid & 15;        // 8 j's each
  const int tb = tid >> 4;        // 4 b's each
  float acc[4][8];
#pragma unroll
  for (int i = 0; i < 4; i++)
#pragma unroll
    for (int j = 0; j < 8; j++) acc[i][j] = 0.f;

  const int lb = tid >> 2, lk = (tid & 3) * 8;    // h2 loader
  const int wj = tid >> 1, wk = (tid & 1) * 16;   // weight loader
  const float* wrow = (wj < 64) ? (muw + (size_t)wj * NM) : (lvw + (size_t)(wj - 64) * NM);

  for (int kc = 0; kc < 256; kc += 32) {
    __syncthreads();
    {
      const bf16* p = h2 + (size_t)(b0 + lb) * NM + (k0 + kc + lk);
#pragma unroll
      for (int i = 0; i < 8; i++) sA[lk + i][lb] = bf2f(p[i]);
      const float* q = wrow + (k0 + kc + wk);
#pragma unroll
      for (int i = 0; i < 16; i++) sW[wk + i][wj] = q[i];
    }
    __syncthreads();
#pragma unroll
    for (int k = 0; k < 32; k++) {
      float av[4], wv[8];
#pragma unroll
      for (int i = 0; i < 4; i++) av[i] = sA[k][tb * 4 + i];
#pragma unroll
      for (int j = 0; j < 8; j++) wv[j] = sW[k][tj * 8 + j];
#pragma unroll
      for (int i = 0; i < 4; i++)
#pragma unroll
        for (int j = 0; j < 8; j++) acc[i][j] += av[i] * wv[j];
    }
  }
#pragma unroll
  for (int i = 0; i < 4; i++)
#pragma unroll
    for (int j = 0; j < 8; j++)
      atomicAdd(&zpre[(size_t)(b0 + tb * 4 + i) * 128 + tj * 8 + j], acc[i][j]);
}

// mu/lv bias + reparameterization; fp32 outputs, fp32 z (ws)
__global__ void zfin(const float* __restrict__ zpre, const float* __restrict__ eps,
                     const float* __restrict__ mub, const float* __restrict__ lvb,
                     float* __restrict__ out_mu, float* __restrict__ out_lv,
                     float* __restrict__ z) {
  const int i = blockIdx.x * 256 + threadIdx.x;   // B*Z = 65536
  const int b = i >> 6, j = i & 63;
  const float mu = zpre[(size_t)b * 128 + j] + mub[j];
  const float lv = zpre[(size_t)b * 128 + 64 + j] + lvb[j];
  const float zz = mu + expf(0.5f * lv) * eps[i];
  out_mu[i] = mu;
  out_lv[i] = lv;
  z[i] = zz;
}

// ---------------------------------------------------------------------------
// Fused decoder branch: fulcon sigmoid + two 2x2 sigmoid block layers + out dot.
// fw staged in LDS per mi-group (fixes 512B-stride uncoalesced global reads).
// Block = 64 b x 256 m; grid (16,16). All fp32.
// ---------------------------------------------------------------------------
__global__ __launch_bounds__(256) void dec_fused(
    const float* __restrict__ z,
    const float* __restrict__ fw, const float* __restrict__ fb,
    const float* __restrict__ hw, const float* __restrict__ hb,
    const float* __restrict__ ow, const float* __restrict__ ob,
    float* __restrict__ out) {
  __shared__ __attribute__((aligned(16))) float sZ[64][68];  // [k][b], 16B-aligned rows
  __shared__ float sFW[64][130];                             // [k][local fw row]
  const int tid = threadIdx.x;
  const int b0 = blockIdx.x * 64;
  const int m0 = blockIdx.y * 256;
  {
    const int r  = tid >> 2;          // b-row 0..63
    const int c0 = (tid & 3) * 16;    // k-chunk
    const float* p = z + (size_t)(b0 + r) * NZ + c0;
#pragma unroll
    for (int i = 0; i < 16; i++) sZ[c0 + i][r] = p[i];
  }

  const int bq = tid >> 6;   // 0..3 : 16-b group
  const int tm = tid & 63;   // lane -> consecutive m

  for (int mi = 0; mi < 4; mi++) {
    const int mb = m0 + mi * 64;        // m-base of this group
    __syncthreads();                    // sFW reuse + (mi==0) sZ ready
    {
      // stage fw rows [2*mb, 2*mb+128) x 64k, transposed: sFW[k][localrow]
      const int R0 = 2 * mb;
#pragma unroll
      for (int q = 0; q < 8; q++) {
        const int v = tid + q * 256;        // 0..2047 float4-ids
        const int grow = v >> 4;            // 0..127
        const int gk = (v & 15) * 4;
        const float4 f4 = *(const float4*)&fw[(size_t)(R0 + grow) * NZ + gk];
        sFW[gk + 0][grow] = f4.x;
        sFW[gk + 1][grow] = f4.y;
        sFW[gk + 2][grow] = f4.z;
        sFW[gk + 3][grow] = f4.w;
      }
    }
    __syncthreads();

    const int m = mb + tm;
    float acc0[16], acc1[16];
    const float bb0 = fb[2 * m], bb1 = fb[2 * m + 1];
#pragma unroll
    for (int b = 0; b < 16; b++) { acc0[b] = bb0; acc1[b] = bb1; }
#pragma unroll 8
    for (int k = 0; k < 64; k++) {
      const float2 wv2 = *(const float2*)&sFW[k][2 * tm];   // 8B-aligned
      const float4 z0 = *(const float4*)&sZ[k][bq * 16 + 0];
      const float4 z1 = *(const float4*)&sZ[k][bq * 16 + 4];
      const float4 z2 = *(const float4*)&sZ[k][bq * 16 + 8];
      const float4 z3 = *(const float4*)&sZ[k][bq * 16 + 12];
      const float zv[16] = {z0.x, z0.y, z0.z, z0.w, z1.x, z1.y, z1.z, z1.w,
                            z2.x, z2.y, z2.z, z2.w, z3.x, z3.y, z3.z, z3.w};
#pragma unroll
      for (int b = 0; b < 16; b++) {
        acc0[b] += zv[b] * wv2.x;
        acc1[b] += zv[b] * wv2.y;
      }
    }
    // tail: 2x2 sigmoid chain + output dot (coalesced float4/float2 weight reads)
    float wv[2][4], hbv[2][2];
#pragma unroll
    for (int l = 0; l < 2; l++) {
      const float4 wp = *(const float4*)&hw[((size_t)l * NM + m) * 4];  // [v][w] 2x2
      wv[l][0] = wp.x; wv[l][1] = wp.y; wv[l][2] = wp.z; wv[l][3] = wp.w;
      const float2 hb2 = *(const float2*)&hb[(size_t)l * NH + 2 * m];
      hbv[l][0] = hb2.x; hbv[l][1] = hb2.y;
    }
    const float2 o2 = *(const float2*)&ow[2 * m];
    const float obv = ob[m];
#pragma unroll
    for (int b = 0; b < 16; b++) {
      float a0 = sigf(acc0[b]), a1 = sigf(acc1[b]);
#pragma unroll
      for (int l = 0; l < 2; l++) {
        const float v0 = sigf(wv[l][0] * a0 + wv[l][1] * a1 + hbv[l][0]);
        const float v1 = sigf(wv[l][2] * a0 + wv[l][3] * a1 + hbv[l][1]);
        a0 = v0; a1 = v1;
      }
      out[(size_t)(b0 + bq * 16 + b) * NM + m] = a0 * o2.x + a1 * o2.y + obv;
    }
  }
}

extern "C" void kernel_launch(void* const* d_in, const int* in_sizes, int n_in,
                              void* d_out, int out_size, void* d_ws, size_t ws_size,
                              hipStream_t stream) {
  const float* x   = (const float*)d_in[0];
  const float* eps = (const float*)d_in[1];
  const float* e1w = (const float*)d_in[2];
  const float* e1b = (const float*)d_in[3];
  const float* e2w = (const float*)d_in[4];
  const float* e2b = (const float*)d_in[5];
  const float* muw = (const float*)d_in[6];
  const float* mub = (const float*)d_in[7];
  const float* lvw = (const float*)d_in[8];
  const float* lvb = (const float*)d_in[9];
  const float* mfw = (const float*)d_in[10];
  const float* mfb = (const float*)d_in[11];
  const float* mhw = (const float*)d_in[12];
  const float* mhb = (const float*)d_in[13];
  const float* mow = (const float*)d_in[14];
  const float* mob = (const float*)d_in[15];
  const float* cfw = (const float*)d_in[16];
  const float* cfb = (const float*)d_in[17];
  const float* chw = (const float*)d_in[18];
  const float* chb = (const float*)d_in[19];
  const float* cow = (const float*)d_in[20];
  const float* cob = (const float*)d_in[21];

  // d_out regions (fp32 elements): out_x [0,4M), out_lc [4M,8M), mu, lv.
  // bf16 intermediates overlay dead byte-ranges:
  //   h1 bf16 @ bytes [0,8M)      (dead after enc2; dec-mean overwrites)
  //   xb bf16 @ bytes [16M,24M)   (dead after enc1)
  //   h2 bf16 @ bytes [16M,24M)   (overwrites xb; dead after mulv; dec-cov overwrites)
  char* ob_ = (char*)d_out;
  float* out_x  = (float*)ob_;
  float* out_lc = (float*)(ob_ + (16u << 20));
  float* out_mu = out_x + (size_t)2 * NB * NM;
  float* out_lv = out_mu + (size_t)NB * NZ;
  bf16* h1 = (bf16*)ob_;
  bf16* xb = (bf16*)(ob_ + (16u << 20));
  bf16* h2 = xb;

  // ws: zpre fp32 512KB + z fp32 256KB = 768KB (round-4-proven budget)
  float* zpre = (float*)d_ws;
  float* z    = (float*)((char*)d_ws + (1u << 19));

  cvt_f32_bf16<<<dim3(4096), 256, 0, stream>>>(x, xb, NB * NM / 4);
  zero_f32<<<dim3(512), 256, 0, stream>>>(zpre, NB * 128);
  gemm_nt<<<dim3(8, 64), 256, 0, stream>>>(xb, e1w, e1b, h1, NM, NM);
  gemm_nt<<<dim3(8, 64), 256, 0, stream>>>(h1, e2w, e2b, h2, NM, NM);
  mulv_splitk<<<dim3(16, 16), 256, 0, stream>>>(h2, muw, lvw, zpre);
  zfin<<<dim3(256), 256, 0, stream>>>(zpre, eps, mub, lvb, out_mu, out_lv, z);
  dec_fused<<<dim3(16, 16), 256, 0, stream>>>(z, mfw, mfb, mhw, mhb, mow, mob, out_x);
  dec_fused<<<dim3(16, 16), 256, 0, stream>>>(z, cfw, cfb, chw, chb, cow, cob, out_lc);
}

// Round 2
// 523.965 us; speedup vs baseline: 1.1669x; 1.0413x over previous
//
#include <hip/hip_runtime.h>
#include <hip/hip_bf16.h>
#include <stdint.h>

typedef __hip_bfloat16 bf16;
typedef __bf16 bf16x8 __attribute__((ext_vector_type(8)));
typedef float f32x4 __attribute__((ext_vector_type(4)));

#define NB 1024
#define NM 4096
#define NZ 64
#define NH 8192

__device__ __forceinline__ float bf2f(bf16 x) { return __bfloat162float(x); }
__device__ __forceinline__ bf16 f2bf(float x) { return __float2bfloat16(x); }
__device__ __forceinline__ float sigf(float x) { return 1.f / (1.f + __expf(-x)); }

// fp32 x -> bf16 (4 elements/thread)
__global__ __launch_bounds__(256) void cvt_f32_bf16(const float* __restrict__ src,
                                                    bf16* __restrict__ dst, int n4) {
  const int i = blockIdx.x * 256 + threadIdx.x;
  if (i >= n4) return;
  const float4 v = ((const float4*)src)[i];
  bf16 o[4] = {f2bf(v.x), f2bf(v.y), f2bf(v.z), f2bf(v.w)};
  *(short4*)&dst[i * 4] = *(short4*)o;
}

__global__ void zero_f32(float* p, int n) {
  int i = blockIdx.x * blockDim.x + threadIdx.x;
  if (i < n) p[i] = 0.f;
}

// ---------------------------------------------------------------------------
// MFMA NT GEMM v3: C[r,c] = relu( sum_k A[r,k]*W[c,k] + bias[c] )
// A bf16 (pre-converted), W fp32 (converted in staging), bias fp32, C bf16.
// Tile 128x64, BK=64, 256 threads = 4 waves (2x2), wave -> 64x32 C sub-tile.
// v3: T3 minimum 2-phase double-buffer — stage tile t+1 BEFORE computing tile
// t, ONE barrier per K-step. vmcnt(0) at the barrier now waits on loads issued
// a full compute-phase earlier (latency hidden), instead of this tile's loads.
//  - grid 8x64 = 512 blocks = 2 blocks/CU; XCD-bijective swizzle (512%8==0)
//  - A via global_load_lds width=16 (linear dest, inverse-swizzled source)
//  - both LDS tiles XOR-swizzled: elem ^= (row&7)<<3 (bank conflicts == 0, r1)
// ---------------------------------------------------------------------------
__global__ __launch_bounds__(256) void gemm_nt(const bf16* __restrict__ A,
                                               const float* __restrict__ W,
                                               const float* __restrict__ bias,
                                               bf16* __restrict__ C,
                                               int K, int N) {
  __shared__ __attribute__((aligned(16))) bf16 smA[2][128 * 64];  // 32 KB
  __shared__ __attribute__((aligned(16))) bf16 smB[2][64 * 64];   // 16 KB
  const int tid  = threadIdx.x;
  const int lane = tid & 63;
  const int w    = tid >> 6;   // 0..3
  const int wr   = w >> 1;     // 0..1 : 64-row group
  const int wc   = w & 1;      // 0..1 : 32-col group

  // XCD-bijective swizzle (hw linear id: x fastest, gridDim.x == 8)
  const int lid  = blockIdx.y * 8 + blockIdx.x;   // 0..511
  const int wgid = (lid & 7) * 64 + (lid >> 3);   // per-XCD contiguous chunk
  const int row0 = (wgid & 7) * 128;
  const int col0 = (wgid >> 3) * 64;

  f32x4 acc[4][2];
#pragma unroll
  for (int i = 0; i < 4; i++)
#pragma unroll
    for (int j = 0; j < 2; j++) acc[i][j] = (f32x4){0.f, 0.f, 0.f, 0.f};

  // W staging map: thread -> smB row tid>>2, k elems [(tid&3)*16, +16)
  const int swr = tid >> 2;
  const int swk = (tid & 3) * 16;
  const float* wp = W + (size_t)(col0 + swr) * K + swk;
  const int swz = (swr & 7) << 3;   // element XOR for this row
  const int woff0 = swr * 64 + ((swk + 0) ^ swz);
  const int woff1 = swr * 64 + ((swk + 8) ^ swz);

  // A -> LDS[buf] for K-base kk: linear dest (wave-uniform base + lane*16),
  // global source inverse-swizzled so swizzled reads see A[r][ke]
  auto stage_A = [&](int buf, int kk) {
#pragma unroll
    for (int q = 0; q < 4; q++) {
      const int chunk = q * 256 + w * 64 + lane;
      const int r  = chunk >> 3;
      const int ke = ((chunk & 7) ^ (r & 7)) * 8;
      __builtin_amdgcn_global_load_lds(
          (__attribute__((address_space(1))) unsigned int*)(A + (size_t)(row0 + r) * K + (kk + ke)),
          (__attribute__((address_space(3))) unsigned int*)(&smA[buf][(q * 256 + w * 64) * 8]),
          16, 0, 0);
    }
  };

  auto write_W = [&](int buf, const float4& a, const float4& b,
                     const float4& c, const float4& d) {
    bf16 t[16] = {f2bf(a.x), f2bf(a.y), f2bf(a.z), f2bf(a.w),
                  f2bf(b.x), f2bf(b.y), f2bf(b.z), f2bf(b.w),
                  f2bf(c.x), f2bf(c.y), f2bf(c.z), f2bf(c.w),
                  f2bf(d.x), f2bf(d.y), f2bf(d.z), f2bf(d.w)};
    *(bf16x8*)&smB[buf][woff0] = ((bf16x8*)t)[0];
    *(bf16x8*)&smB[buf][woff1] = ((bf16x8*)t)[1];
  };

  auto compute = [&](int buf) {
#pragma unroll
    for (int ks = 0; ks < 64; ks += 32) {
      const int kq = ks + (lane >> 4) * 8;   // frag: [m|n = lane&15][k = quad*8+j]
      bf16x8 af[4], bfr[2];
#pragma unroll
      for (int i = 0; i < 4; i++) {
        const int r = wr * 64 + i * 16 + (lane & 15);
        af[i] = *(const bf16x8*)&smA[buf][r * 64 + (kq ^ ((r & 7) << 3))];
      }
#pragma unroll
      for (int j = 0; j < 2; j++) {
        const int r = wc * 32 + j * 16 + (lane & 15);
        bfr[j] = *(const bf16x8*)&smB[buf][r * 64 + (kq ^ ((r & 7) << 3))];
      }
#pragma unroll
      for (int i = 0; i < 4; i++)
#pragma unroll
        for (int j = 0; j < 2; j++)
          acc[i][j] = __builtin_amdgcn_mfma_f32_16x16x32_bf16(af[i], bfr[j], acc[i][j], 0, 0, 0);
    }
  };

  // prologue: stage tile 0 into buf 0
  stage_A(0, 0);
  {
    const float4 a = *(const float4*)(wp + 0);
    const float4 b = *(const float4*)(wp + 4);
    const float4 c = *(const float4*)(wp + 8);
    const float4 d = *(const float4*)(wp + 12);
    write_W(0, a, b, c, d);
  }
  __syncthreads();

  int cur = 0;
  for (int k0 = 64; k0 < K; k0 += 64) {
    // issue next tile's staging first (latency hides under compute below)
    stage_A(cur ^ 1, k0);
    const float4 a = *(const float4*)(wp + k0);
    const float4 b = *(const float4*)(wp + k0 + 4);
    const float4 c = *(const float4*)(wp + k0 + 8);
    const float4 d = *(const float4*)(wp + k0 + 12);
    compute(cur);                 // MFMA on current tile (independent of loads)
    write_W(cur ^ 1, a, b, c, d); // compiler waits W-load vmcnt here, after MFMA
    __syncthreads();              // drains A-gloads (issued one phase ago)
    cur ^= 1;
  }
  compute(cur);   // last tile, no prefetch

  // C/D layout: col = lane&15, row = (lane>>4)*4 + t   [m89-verified]
#pragma unroll
  for (int i = 0; i < 4; i++) {
#pragma unroll
    for (int j = 0; j < 2; j++) {
      const int cc = col0 + wc * 32 + j * 16 + (lane & 15);
      const float bs = bias[cc];
#pragma unroll
      for (int t = 0; t < 4; t++) {
        const int rr = row0 + wr * 64 + i * 16 + (lane >> 4) * 4 + t;
        float v = acc[i][j][t] + bs;
        v = v > 0.f ? v : 0.f;   // relu (both encoder layers)
        C[(size_t)rr * N + cc] = f2bf(v);
      }
    }
  }
}

// ---------------------------------------------------------------------------
// mu/logvar split-K: zpre[b, 0..63]=mu-dot, [64..127]=lv-dot (fp32 atomics).
// A = h2 bf16, weights fp32. grid (16 b-tiles, 16 k-chunks of 256), block 256.
// ---------------------------------------------------------------------------
__global__ __launch_bounds__(256) void mulv_splitk(const bf16* __restrict__ h2,
                                                   const float* __restrict__ muw,
                                                   const float* __restrict__ lvw,
                                                   float* __restrict__ zpre) {
  __shared__ float sA[32][64];    // [k][b]
  __shared__ float sW[32][128];   // [k][j]
  const int tid = threadIdx.x;
  const int b0 = blockIdx.x * 64;
  const int k0 = blockIdx.y * 256;
  const int tj = tid & 15;        // 8 j's each
  const int tb = tid >> 4;        // 4 b's each
  float acc[4][8];
#pragma unroll
  for (int i = 0; i < 4; i++)
#pragma unroll
    for (int j = 0; j < 8; j++) acc[i][j] = 0.f;

  const int lb = tid >> 2, lk = (tid & 3) * 8;    // h2 loader
  const int wj = tid >> 1, wk = (tid & 1) * 16;   // weight loader
  const float* wrow = (wj < 64) ? (muw + (size_t)wj * NM) : (lvw + (size_t)(wj - 64) * NM);

  for (int kc = 0; kc < 256; kc += 32) {
    __syncthreads();
    {
      const bf16* p = h2 + (size_t)(b0 + lb) * NM + (k0 + kc + lk);
#pragma unroll
      for (int i = 0; i < 8; i++) sA[lk + i][lb] = bf2f(p[i]);
      const float* q = wrow + (k0 + kc + wk);
#pragma unroll
      for (int i = 0; i < 16; i++) sW[wk + i][wj] = q[i];
    }
    __syncthreads();
#pragma unroll
    for (int k = 0; k < 32; k++) {
      float av[4], wv[8];
#pragma unroll
      for (int i = 0; i < 4; i++) av[i] = sA[k][tb * 4 + i];
#pragma unroll
      for (int j = 0; j < 8; j++) wv[j] = sW[k][tj * 8 + j];
#pragma unroll
      for (int i = 0; i < 4; i++)
#pragma unroll
        for (int j = 0; j < 8; j++) acc[i][j] += av[i] * wv[j];
    }
  }
#pragma unroll
  for (int i = 0; i < 4; i++)
#pragma unroll
    for (int j = 0; j < 8; j++)
      atomicAdd(&zpre[(size_t)(b0 + tb * 4 + i) * 128 + tj * 8 + j], acc[i][j]);
}

// mu/lv bias + reparameterization; fp32 outputs, fp32 z (ws)
__global__ void zfin(const float* __restrict__ zpre, const float* __restrict__ eps,
                     const float* __restrict__ mub, const float* __restrict__ lvb,
                     float* __restrict__ out_mu, float* __restrict__ out_lv,
                     float* __restrict__ z) {
  const int i = blockIdx.x * 256 + threadIdx.x;   // B*Z = 65536
  const int b = i >> 6, j = i & 63;
  const float mu = zpre[(size_t)b * 128 + j] + mub[j];
  const float lv = zpre[(size_t)b * 128 + 64 + j] + lvb[j];
  const float zz = mu + expf(0.5f * lv) * eps[i];
  out_mu[i] = mu;
  out_lv[i] = lv;
  z[i] = zz;
}

// ---------------------------------------------------------------------------
// Fused decoder branch: fulcon sigmoid + two 2x2 sigmoid block layers + out dot.
// v2: mi-loop lifted to blockIdx.z -> grid (16,16,4) = 1024 blocks (~3/CU by
// LDS) instead of 256 blocks = 1/CU with a serial stage->barrier->compute x4
// chain. Per-block work quarters; latency hidden by cross-block overlap.
// Block = 64 b x 64 m; all fp32.
// ---------------------------------------------------------------------------
__global__ __launch_bounds__(256) void dec_fused(
    const float* __restrict__ z,
    const float* __restrict__ fw, const float* __restrict__ fb,
    const float* __restrict__ hw, const float* __restrict__ hb,
    const float* __restrict__ ow, const float* __restrict__ ob,
    float* __restrict__ out) {
  __shared__ __attribute__((aligned(16))) float sZ[64][68];  // [k][b], 16B-aligned rows
  __shared__ float sFW[64][130];                             // [k][local fw row]
  const int tid = threadIdx.x;
  const int b0 = blockIdx.x * 64;
  const int m0 = blockIdx.y * 256;
  const int mi = blockIdx.z;          // 0..3 : 64-m group within the 256-m tile
  {
    const int r  = tid >> 2;          // b-row 0..63
    const int c0 = (tid & 3) * 16;    // k-chunk
    const float* p = z + (size_t)(b0 + r) * NZ + c0;
#pragma unroll
    for (int i = 0; i < 16; i++) sZ[c0 + i][r] = p[i];
  }

  const int bq = tid >> 6;   // 0..3 : 16-b group
  const int tm = tid & 63;   // lane -> consecutive m
  const int mb = m0 + mi * 64;        // m-base of this block

  {
    // stage fw rows [2*mb, 2*mb+128) x 64k, transposed: sFW[k][localrow]
    const int R0 = 2 * mb;
#pragma unroll
    for (int q = 0; q < 8; q++) {
      const int v = tid + q * 256;        // 0..2047 float4-ids
      const int grow = v >> 4;            // 0..127
      const int gk = (v & 15) * 4;
      const float4 f4 = *(const float4*)&fw[(size_t)(R0 + grow) * NZ + gk];
      sFW[gk + 0][grow] = f4.x;
      sFW[gk + 1][grow] = f4.y;
      sFW[gk + 2][grow] = f4.z;
      sFW[gk + 3][grow] = f4.w;
    }
  }
  __syncthreads();

  const int m = mb + tm;
  float acc0[16], acc1[16];
  const float bb0 = fb[2 * m], bb1 = fb[2 * m + 1];
#pragma unroll
  for (int b = 0; b < 16; b++) { acc0[b] = bb0; acc1[b] = bb1; }
#pragma unroll 8
  for (int k = 0; k < 64; k++) {
    const float2 wv2 = *(const float2*)&sFW[k][2 * tm];   // 8B-aligned
    const float4 z0 = *(const float4*)&sZ[k][bq * 16 + 0];
    const float4 z1 = *(const float4*)&sZ[k][bq * 16 + 4];
    const float4 z2 = *(const float4*)&sZ[k][bq * 16 + 8];
    const float4 z3 = *(const float4*)&sZ[k][bq * 16 + 12];
    const float zv[16] = {z0.x, z0.y, z0.z, z0.w, z1.x, z1.y, z1.z, z1.w,
                          z2.x, z2.y, z2.z, z2.w, z3.x, z3.y, z3.z, z3.w};
#pragma unroll
    for (int b = 0; b < 16; b++) {
      acc0[b] += zv[b] * wv2.x;
      acc1[b] += zv[b] * wv2.y;
    }
  }
  // tail: 2x2 sigmoid chain + output dot (coalesced float4/float2 weight reads)
  float wv[2][4], hbv[2][2];
#pragma unroll
  for (int l = 0; l < 2; l++) {
    const float4 wp = *(const float4*)&hw[((size_t)l * NM + m) * 4];  // [v][w] 2x2
    wv[l][0] = wp.x; wv[l][1] = wp.y; wv[l][2] = wp.z; wv[l][3] = wp.w;
    const float2 hb2 = *(const float2*)&hb[(size_t)l * NH + 2 * m];
    hbv[l][0] = hb2.x; hbv[l][1] = hb2.y;
  }
  const float2 o2 = *(const float2*)&ow[2 * m];
  const float obv = ob[m];
#pragma unroll
  for (int b = 0; b < 16; b++) {
    float a0 = sigf(acc0[b]), a1 = sigf(acc1[b]);
#pragma unroll
    for (int l = 0; l < 2; l++) {
      const float v0 = sigf(wv[l][0] * a0 + wv[l][1] * a1 + hbv[l][0]);
      const float v1 = sigf(wv[l][2] * a0 + wv[l][3] * a1 + hbv[l][1]);
      a0 = v0; a1 = v1;
    }
    out[(size_t)(b0 + bq * 16 + b) * NM + m] = a0 * o2.x + a1 * o2.y + obv;
  }
}

extern "C" void kernel_launch(void* const* d_in, const int* in_sizes, int n_in,
                              void* d_out, int out_size, void* d_ws, size_t ws_size,
                              hipStream_t stream) {
  const float* x   = (const float*)d_in[0];
  const float* eps = (const float*)d_in[1];
  const float* e1w = (const float*)d_in[2];
  const float* e1b = (const float*)d_in[3];
  const float* e2w = (const float*)d_in[4];
  const float* e2b = (const float*)d_in[5];
  const float* muw = (const float*)d_in[6];
  const float* mub = (const float*)d_in[7];
  const float* lvw = (const float*)d_in[8];
  const float* lvb = (const float*)d_in[9];
  const float* mfw = (const float*)d_in[10];
  const float* mfb = (const float*)d_in[11];
  const float* mhw = (const float*)d_in[12];
  const float* mhb = (const float*)d_in[13];
  const float* mow = (const float*)d_in[14];
  const float* mob = (const float*)d_in[15];
  const float* cfw = (const float*)d_in[16];
  const float* cfb = (const float*)d_in[17];
  const float* chw = (const float*)d_in[18];
  const float* chb = (const float*)d_in[19];
  const float* cow = (const float*)d_in[20];
  const float* cob = (const float*)d_in[21];

  // d_out regions (fp32 elements): out_x [0,4M), out_lc [4M,8M), mu, lv.
  // bf16 intermediates overlay dead byte-ranges:
  //   h1 bf16 @ bytes [0,8M)      (dead after enc2; dec-mean overwrites)
  //   xb bf16 @ bytes [16M,24M)   (dead after enc1)
  //   h2 bf16 @ bytes [16M,24M)   (overwrites xb; dead after mulv; dec-cov overwrites)
  char* ob_ = (char*)d_out;
  float* out_x  = (float*)ob_;
  float* out_lc = (float*)(ob_ + (16u << 20));
  float* out_mu = out_x + (size_t)2 * NB * NM;
  float* out_lv = out_mu + (size_t)NB * NZ;
  bf16* h1 = (bf16*)ob_;
  bf16* xb = (bf16*)(ob_ + (16u << 20));
  bf16* h2 = xb;

  // ws: zpre fp32 512KB + z fp32 256KB = 768KB (round-4-proven budget)
  float* zpre = (float*)d_ws;
  float* z    = (float*)((char*)d_ws + (1u << 19));

  cvt_f32_bf16<<<dim3(4096), 256, 0, stream>>>(x, xb, NB * NM / 4);
  zero_f32<<<dim3(512), 256, 0, stream>>>(zpre, NB * 128);
  gemm_nt<<<dim3(8, 64), 256, 0, stream>>>(xb, e1w, e1b, h1, NM, NM);
  gemm_nt<<<dim3(8, 64), 256, 0, stream>>>(h1, e2w, e2b, h2, NM, NM);
  mulv_splitk<<<dim3(16, 16), 256, 0, stream>>>(h2, muw, lvw, zpre);
  zfin<<<dim3(256), 256, 0, stream>>>(zpre, eps, mub, lvb, out_mu, out_lv, z);
  dec_fused<<<dim3(16, 16, 4), 256, 0, stream>>>(z, mfw, mfb, mhw, mhb, mow, mob, out_x);
  dec_fused<<<dim3(16, 16, 4), 256, 0, stream>>>(z, cfw, cfb, chw, chb, cow, cob, out_lc);
}

// Round 3
// 504.106 us; speedup vs baseline: 1.2128x; 1.0394x over previous
//
#include <hip/hip_runtime.h>
#include <hip/hip_bf16.h>
#include <stdint.h>

typedef __hip_bfloat16 bf16;
typedef __bf16 bf16x8 __attribute__((ext_vector_type(8)));
typedef float f32x4 __attribute__((ext_vector_type(4)));

#define NB 1024
#define NM 4096
#define NZ 64
#define NH 8192

__device__ __forceinline__ float bf2f(bf16 x) { return __bfloat162float(x); }
__device__ __forceinline__ bf16 f2bf(float x) { return __float2bfloat16(x); }
__device__ __forceinline__ float sigf(float x) { return 1.f / (1.f + __expf(-x)); }

// fp32 x -> bf16 (4 elements/thread)
__global__ __launch_bounds__(256) void cvt_f32_bf16(const float* __restrict__ src,
                                                    bf16* __restrict__ dst, int n4) {
  const int i = blockIdx.x * 256 + threadIdx.x;
  if (i >= n4) return;
  const float4 v = ((const float4*)src)[i];
  bf16 o[4] = {f2bf(v.x), f2bf(v.y), f2bf(v.z), f2bf(v.w)};
  *(short4*)&dst[i * 4] = *(short4*)o;
}

__global__ void zero_f32(float* p, int n) {
  int i = blockIdx.x * blockDim.x + threadIdx.x;
  if (i < n) p[i] = 0.f;
}

#define VMW8 asm volatile("s_waitcnt vmcnt(8)" ::: "memory")
#define VMW0 asm volatile("s_waitcnt vmcnt(0)" ::: "memory")
#define LGKM0 asm volatile("s_waitcnt lgkmcnt(0)" ::: "memory")

// ---------------------------------------------------------------------------
// MFMA NT GEMM v4: C[r,c] = relu( sum_k A[r,k]*W[c,k] + bias[c] )
// Counted-vmcnt pipeline (T4): raw s_barrier + s_waitcnt vmcnt(8) — tile i+1's
// 8 VMEM ops (4x W float4, 4x A global_load_lds) stay IN FLIGHT across the
// barrier, draining only at iter i+1 after a full iteration of latency cover.
// Slots: A mod-3 (stage into (i+2)%3, freed by barrier(i) = compute(i-1) done
// by ALL waves), W mod-2 (rewritten at i+2, last read compute(i) done by all
// at barrier(i+1)). vmcnt FIFO: [W(i+1)4, A(i+1)4, W(i+2)4, A(i+2)4];
// "memory"-clobbered asm waits pin group order. Tile 128x64, 256 thr, 4 waves.
// grid 8x64 = 512 = 2 blocks/CU; XCD-bijective swizzle; LDS XOR-swizzle
// (conflicts==0, r1); A gll linear-dest + inverse-swizzled source (rule 21).
// ---------------------------------------------------------------------------
__global__ __launch_bounds__(256) void gemm_nt(const bf16* __restrict__ A,
                                               const float* __restrict__ W,
                                               const float* __restrict__ bias,
                                               bf16* __restrict__ C,
                                               int K, int N) {
  __shared__ __attribute__((aligned(16))) bf16 smA[3][128 * 64];  // 48 KB
  __shared__ __attribute__((aligned(16))) bf16 smB[2][64 * 64];   // 16 KB
  const int tid  = threadIdx.x;
  const int lane = tid & 63;
  const int w    = tid >> 6;   // 0..3
  const int wr   = w >> 1;     // 0..1 : 64-row group
  const int wc   = w & 1;      // 0..1 : 32-col group

  // XCD-bijective swizzle (hw linear id: x fastest, gridDim.x == 8)
  const int lid  = blockIdx.y * 8 + blockIdx.x;   // 0..511
  const int wgid = (lid & 7) * 64 + (lid >> 3);   // per-XCD contiguous chunk
  const int row0 = (wgid & 7) * 128;
  const int col0 = (wgid >> 3) * 64;

  f32x4 acc[4][2];
#pragma unroll
  for (int i = 0; i < 4; i++)
#pragma unroll
    for (int j = 0; j < 2; j++) acc[i][j] = (f32x4){0.f, 0.f, 0.f, 0.f};

  // W staging map: thread -> smB row tid>>2, k elems [(tid&3)*16, +16)
  const int swr = tid >> 2;
  const int swk = (tid & 3) * 16;
  const float* wp = W + (size_t)(col0 + swr) * K + swk;
  const int swz = (swr & 7) << 3;   // element XOR for this row
  const int woff0 = swr * 64 + ((swk + 0) ^ swz);
  const int woff1 = swr * 64 + ((swk + 8) ^ swz);

  auto load_W = [&](float4 (&wv)[4], int kk) {
    wv[0] = *(const float4*)(wp + kk);
    wv[1] = *(const float4*)(wp + kk + 4);
    wv[2] = *(const float4*)(wp + kk + 8);
    wv[3] = *(const float4*)(wp + kk + 12);
  };

  auto stage_A = [&](int slot, int kk) {
#pragma unroll
    for (int q = 0; q < 4; q++) {
      const int chunk = q * 256 + w * 64 + lane;
      const int r  = chunk >> 3;
      const int ke = ((chunk & 7) ^ (r & 7)) * 8;
      __builtin_amdgcn_global_load_lds(
          (__attribute__((address_space(1))) unsigned int*)(A + (size_t)(row0 + r) * K + (kk + ke)),
          (__attribute__((address_space(3))) unsigned int*)(&smA[slot][(q * 256 + w * 64) * 8]),
          16, 0, 0);
    }
  };

  auto write_W = [&](int slot, const float4 (&wv)[4]) {
    bf16 t[16] = {f2bf(wv[0].x), f2bf(wv[0].y), f2bf(wv[0].z), f2bf(wv[0].w),
                  f2bf(wv[1].x), f2bf(wv[1].y), f2bf(wv[1].z), f2bf(wv[1].w),
                  f2bf(wv[2].x), f2bf(wv[2].y), f2bf(wv[2].z), f2bf(wv[2].w),
                  f2bf(wv[3].x), f2bf(wv[3].y), f2bf(wv[3].z), f2bf(wv[3].w)};
    *(bf16x8*)&smB[slot][woff0] = ((bf16x8*)t)[0];
    *(bf16x8*)&smB[slot][woff1] = ((bf16x8*)t)[1];
  };

  auto compute = [&](int sa, int ws) {
#pragma unroll
    for (int ks = 0; ks < 64; ks += 32) {
      const int kq = ks + (lane >> 4) * 8;   // frag: [m|n = lane&15][k = quad*8+j]
      bf16x8 af[4], bfr[2];
#pragma unroll
      for (int i = 0; i < 4; i++) {
        const int r = wr * 64 + i * 16 + (lane & 15);
        af[i] = *(const bf16x8*)&smA[sa][r * 64 + (kq ^ ((r & 7) << 3))];
      }
#pragma unroll
      for (int j = 0; j < 2; j++) {
        const int r = wc * 32 + j * 16 + (lane & 15);
        bfr[j] = *(const bf16x8*)&smB[ws][r * 64 + (kq ^ ((r & 7) << 3))];
      }
#pragma unroll
      for (int i = 0; i < 4; i++)
#pragma unroll
        for (int j = 0; j < 2; j++)
          acc[i][j] = __builtin_amdgcn_mfma_f32_16x16x32_bf16(af[i], bfr[j], acc[i][j], 0, 0, 0);
    }
  };

  const int K64 = K >> 6;   // 64 K-steps; even, >= 4
  float4 wA[4], wB[4];

  // prologue: tiles 0 and 1 in flight. Empty-asm fence keeps FIFO group order
  // [W0,A0 | W1,A1] so vmcnt(8) drains exactly tile 0.
  load_W(wA, 0);
  stage_A(0, 0);
  asm volatile("" ::: "memory");
  load_W(wB, 64);
  stage_A(1, 64);

  int sa = 0;   // compute slot of the even body; tile t lives in slot t%3
  for (int i = 0; i + 2 < K64; i += 2) {
    const int nx  = (sa + 1 == 3) ? 0 : sa + 1;
    const int nnx = (nx + 1 == 3) ? 0 : nx + 1;
    // ---- body i (even, W slot 0) ----
    VMW8;                      // tile i drained; i+1 stays in flight
    write_W(0, wA);
    LGKM0;
    __builtin_amdgcn_s_barrier();
    __builtin_amdgcn_sched_barrier(0);
    load_W(wA, (i + 2) * 64);
    stage_A(nnx, (i + 2) * 64);
    compute(sa, 0);
    // ---- body i+1 (odd, W slot 1) ----
    VMW8;
    write_W(1, wB);
    LGKM0;
    __builtin_amdgcn_s_barrier();
    __builtin_amdgcn_sched_barrier(0);
    load_W(wB, (i + 3) * 64);
    stage_A(sa, (i + 3) * 64);
    compute(nx, 1);
    sa = nnx;
  }
  // peel i = K64-2 (even, W slot 0)
  VMW8;
  write_W(0, wA);
  LGKM0;
  __builtin_amdgcn_s_barrier();
  __builtin_amdgcn_sched_barrier(0);
  compute(sa, 0);
  // peel i = K64-1 (odd, W slot 1)
  VMW0;
  write_W(1, wB);
  LGKM0;
  __builtin_amdgcn_s_barrier();
  __builtin_amdgcn_sched_barrier(0);
  compute((sa + 1 == 3) ? 0 : sa + 1, 1);

  // C/D layout: col = lane&15, row = (lane>>4)*4 + t   [m89-verified]
#pragma unroll
  for (int i = 0; i < 4; i++) {
#pragma unroll
    for (int j = 0; j < 2; j++) {
      const int cc = col0 + wc * 32 + j * 16 + (lane & 15);
      const float bs = bias[cc];
#pragma unroll
      for (int t = 0; t < 4; t++) {
        const int rr = row0 + wr * 64 + i * 16 + (lane >> 4) * 4 + t;
        float v = acc[i][j][t] + bs;
        v = v > 0.f ? v : 0.f;   // relu (both encoder layers)
        C[(size_t)rr * N + cc] = f2bf(v);
      }
    }
  }
}

// ---------------------------------------------------------------------------
// mu/logvar split-K: zpre[b, 0..63]=mu-dot, [64..127]=lv-dot (fp32 atomics).
// A = h2 bf16, weights fp32. grid (16 b-tiles, 16 k-chunks of 256), block 256.
// v2: vectorized staging (1x16B bf16 load + 4x float4) replacing 24 scalar
// loads/thread/iter (Common-mistake #2).
// ---------------------------------------------------------------------------
__global__ __launch_bounds__(256) void mulv_splitk(const bf16* __restrict__ h2,
                                                   const float* __restrict__ muw,
                                                   const float* __restrict__ lvw,
                                                   float* __restrict__ zpre) {
  __shared__ float sA[32][64];    // [k][b]
  __shared__ float sW[32][128];   // [k][j]
  const int tid = threadIdx.x;
  const int b0 = blockIdx.x * 64;
  const int k0 = blockIdx.y * 256;
  const int tj = tid & 15;        // 8 j's each
  const int tb = tid >> 4;        // 4 b's each
  float acc[4][8];
#pragma unroll
  for (int i = 0; i < 4; i++)
#pragma unroll
    for (int j = 0; j < 8; j++) acc[i][j] = 0.f;

  const int lb = tid >> 2, lk = (tid & 3) * 8;    // h2 loader
  const int wj = tid >> 1, wk = (tid & 1) * 16;   // weight loader
  const float* wrow = (wj < 64) ? (muw + (size_t)wj * NM) : (lvw + (size_t)(wj - 64) * NM);

  for (int kc = 0; kc < 256; kc += 32) {
    __syncthreads();
    {
      // h2: one 16B load = 8 bf16; bf16->f32 is a 16-bit shift
      const uint4 v = *(const uint4*)(h2 + (size_t)(b0 + lb) * NM + (k0 + kc + lk));
      sA[lk + 0][lb] = __uint_as_float(v.x << 16);
      sA[lk + 1][lb] = __uint_as_float(v.x & 0xffff0000u);
      sA[lk + 2][lb] = __uint_as_float(v.y << 16);
      sA[lk + 3][lb] = __uint_as_float(v.y & 0xffff0000u);
      sA[lk + 4][lb] = __uint_as_float(v.z << 16);
      sA[lk + 5][lb] = __uint_as_float(v.z & 0xffff0000u);
      sA[lk + 6][lb] = __uint_as_float(v.w << 16);
      sA[lk + 7][lb] = __uint_as_float(v.w & 0xffff0000u);
      const float* q = wrow + (k0 + kc + wk);
#pragma unroll
      for (int i = 0; i < 4; i++) {
        const float4 f = *(const float4*)(q + i * 4);
        sW[wk + i * 4 + 0][wj] = f.x;
        sW[wk + i * 4 + 1][wj] = f.y;
        sW[wk + i * 4 + 2][wj] = f.z;
        sW[wk + i * 4 + 3][wj] = f.w;
      }
    }
    __syncthreads();
#pragma unroll
    for (int k = 0; k < 32; k++) {
      float av[4], wv[8];
#pragma unroll
      for (int i = 0; i < 4; i++) av[i] = sA[k][tb * 4 + i];
#pragma unroll
      for (int j = 0; j < 8; j++) wv[j] = sW[k][tj * 8 + j];
#pragma unroll
      for (int i = 0; i < 4; i++)
#pragma unroll
        for (int j = 0; j < 8; j++) acc[i][j] += av[i] * wv[j];
    }
  }
#pragma unroll
  for (int i = 0; i < 4; i++)
#pragma unroll
    for (int j = 0; j < 8; j++)
      atomicAdd(&zpre[(size_t)(b0 + tb * 4 + i) * 128 + tj * 8 + j], acc[i][j]);
}

// mu/lv bias + reparameterization; fp32 outputs, fp32 z (ws)
__global__ void zfin(const float* __restrict__ zpre, const float* __restrict__ eps,
                     const float* __restrict__ mub, const float* __restrict__ lvb,
                     float* __restrict__ out_mu, float* __restrict__ out_lv,
                     float* __restrict__ z) {
  const int i = blockIdx.x * 256 + threadIdx.x;   // B*Z = 65536
  const int b = i >> 6, j = i & 63;
  const float mu = zpre[(size_t)b * 128 + j] + mub[j];
  const float lv = zpre[(size_t)b * 128 + 64 + j] + lvb[j];
  const float zz = mu + expf(0.5f * lv) * eps[i];
  out_mu[i] = mu;
  out_lv[i] = lv;
  z[i] = zz;
}

// ---------------------------------------------------------------------------
// Fused decoder branch: fulcon sigmoid + two 2x2 sigmoid block layers + out dot.
// grid (16,16,4) = 1024 blocks; block = 64 b x 64 m; all fp32.
// ---------------------------------------------------------------------------
__global__ __launch_bounds__(256) void dec_fused(
    const float* __restrict__ z,
    const float* __restrict__ fw, const float* __restrict__ fb,
    const float* __restrict__ hw, const float* __restrict__ hb,
    const float* __restrict__ ow, const float* __restrict__ ob,
    float* __restrict__ out) {
  __shared__ __attribute__((aligned(16))) float sZ[64][68];  // [k][b], 16B-aligned rows
  __shared__ float sFW[64][130];                             // [k][local fw row]
  const int tid = threadIdx.x;
  const int b0 = blockIdx.x * 64;
  const int m0 = blockIdx.y * 256;
  const int mi = blockIdx.z;          // 0..3 : 64-m group within the 256-m tile
  {
    const int r  = tid >> 2;          // b-row 0..63
    const int c0 = (tid & 3) * 16;    // k-chunk
    const float* p = z + (size_t)(b0 + r) * NZ + c0;
#pragma unroll
    for (int i = 0; i < 16; i++) sZ[c0 + i][r] = p[i];
  }

  const int bq = tid >> 6;   // 0..3 : 16-b group
  const int tm = tid & 63;   // lane -> consecutive m
  const int mb = m0 + mi * 64;        // m-base of this block

  {
    // stage fw rows [2*mb, 2*mb+128) x 64k, transposed: sFW[k][localrow]
    const int R0 = 2 * mb;
#pragma unroll
    for (int q = 0; q < 8; q++) {
      const int v = tid + q * 256;        // 0..2047 float4-ids
      const int grow = v >> 4;            // 0..127
      const int gk = (v & 15) * 4;
      const float4 f4 = *(const float4*)&fw[(size_t)(R0 + grow) * NZ + gk];
      sFW[gk + 0][grow] = f4.x;
      sFW[gk + 1][grow] = f4.y;
      sFW[gk + 2][grow] = f4.z;
      sFW[gk + 3][grow] = f4.w;
    }
  }
  __syncthreads();

  const int m = mb + tm;
  float acc0[16], acc1[16];
  const float bb0 = fb[2 * m], bb1 = fb[2 * m + 1];
#pragma unroll
  for (int b = 0; b < 16; b++) { acc0[b] = bb0; acc1[b] = bb1; }
#pragma unroll 8
  for (int k = 0; k < 64; k++) {
    const float2 wv2 = *(const float2*)&sFW[k][2 * tm];   // 8B-aligned
    const float4 z0 = *(const float4*)&sZ[k][bq * 16 + 0];
    const float4 z1 = *(const float4*)&sZ[k][bq * 16 + 4];
    const float4 z2 = *(const float4*)&sZ[k][bq * 16 + 8];
    const float4 z3 = *(const float4*)&sZ[k][bq * 16 + 12];
    const float zv[16] = {z0.x, z0.y, z0.z, z0.w, z1.x, z1.y, z1.z, z1.w,
                          z2.x, z2.y, z2.z, z2.w, z3.x, z3.y, z3.z, z3.w};
#pragma unroll
    for (int b = 0; b < 16; b++) {
      acc0[b] += zv[b] * wv2.x;
      acc1[b] += zv[b] * wv2.y;
    }
  }
  // tail: 2x2 sigmoid chain + output dot (coalesced float4/float2 weight reads)
  float wv[2][4], hbv[2][2];
#pragma unroll
  for (int l = 0; l < 2; l++) {
    const float4 wp = *(const float4*)&hw[((size_t)l * NM + m) * 4];  // [v][w] 2x2
    wv[l][0] = wp.x; wv[l][1] = wp.y; wv[l][2] = wp.z; wv[l][3] = wp.w;
    const float2 hb2 = *(const float2*)&hb[(size_t)l * NH + 2 * m];
    hbv[l][0] = hb2.x; hbv[l][1] = hb2.y;
  }
  const float2 o2 = *(const float2*)&ow[2 * m];
  const float obv = ob[m];
#pragma unroll
  for (int b = 0; b < 16; b++) {
    float a0 = sigf(acc0[b]), a1 = sigf(acc1[b]);
#pragma unroll
    for (int l = 0; l < 2; l++) {
      const float v0 = sigf(wv[l][0] * a0 + wv[l][1] * a1 + hbv[l][0]);
      const float v1 = sigf(wv[l][2] * a0 + wv[l][3] * a1 + hbv[l][1]);
      a0 = v0; a1 = v1;
    }
    out[(size_t)(b0 + bq * 16 + b) * NM + m] = a0 * o2.x + a1 * o2.y + obv;
  }
}

extern "C" void kernel_launch(void* const* d_in, const int* in_sizes, int n_in,
                              void* d_out, int out_size, void* d_ws, size_t ws_size,
                              hipStream_t stream) {
  const float* x   = (const float*)d_in[0];
  const float* eps = (const float*)d_in[1];
  const float* e1w = (const float*)d_in[2];
  const float* e1b = (const float*)d_in[3];
  const float* e2w = (const float*)d_in[4];
  const float* e2b = (const float*)d_in[5];
  const float* muw = (const float*)d_in[6];
  const float* mub = (const float*)d_in[7];
  const float* lvw = (const float*)d_in[8];
  const float* lvb = (const float*)d_in[9];
  const float* mfw = (const float*)d_in[10];
  const float* mfb = (const float*)d_in[11];
  const float* mhw = (const float*)d_in[12];
  const float* mhb = (const float*)d_in[13];
  const float* mow = (const float*)d_in[14];
  const float* mob = (const float*)d_in[15];
  const float* cfw = (const float*)d_in[16];
  const float* cfb = (const float*)d_in[17];
  const float* chw = (const float*)d_in[18];
  const float* chb = (const float*)d_in[19];
  const float* cow = (const float*)d_in[20];
  const float* cob = (const float*)d_in[21];

  // d_out regions (fp32 elements): out_x [0,4M), out_lc [4M,8M), mu, lv.
  // bf16 intermediates overlay dead byte-ranges:
  //   h1 bf16 @ bytes [0,8M)      (dead after enc2; dec-mean overwrites)
  //   xb bf16 @ bytes [16M,24M)   (dead after enc1)
  //   h2 bf16 @ bytes [16M,24M)   (overwrites xb; dead after mulv; dec-cov overwrites)
  char* ob_ = (char*)d_out;
  float* out_x  = (float*)ob_;
  float* out_lc = (float*)(ob_ + (16u << 20));
  float* out_mu = out_x + (size_t)2 * NB * NM;
  float* out_lv = out_mu + (size_t)NB * NZ;
  bf16* h1 = (bf16*)ob_;
  bf16* xb = (bf16*)(ob_ + (16u << 20));
  bf16* h2 = xb;

  // ws: zpre fp32 512KB + z fp32 256KB = 768KB (round-4-proven budget)
  float* zpre = (float*)d_ws;
  float* z    = (float*)((char*)d_ws + (1u << 19));

  cvt_f32_bf16<<<dim3(4096), 256, 0, stream>>>(x, xb, NB * NM / 4);
  zero_f32<<<dim3(512), 256, 0, stream>>>(zpre, NB * 128);
  gemm_nt<<<dim3(8, 64), 256, 0, stream>>>(xb, e1w, e1b, h1, NM, NM);
  gemm_nt<<<dim3(8, 64), 256, 0, stream>>>(h1, e2w, e2b, h2, NM, NM);
  mulv_splitk<<<dim3(16, 16), 256, 0, stream>>>(h2, muw, lvw, zpre);
  zfin<<<dim3(256), 256, 0, stream>>>(zpre, eps, mub, lvb, out_mu, out_lv, z);
  dec_fused<<<dim3(16, 16, 4), 256, 0, stream>>>(z, mfw, mfb, mhw, mhb, mow, mob, out_x);
  dec_fused<<<dim3(16, 16, 4), 256, 0, stream>>>(z, cfw, cfb, chw, chb, cow, cob, out_lc);
}

// Round 6
// 440.138 us; speedup vs baseline: 1.3891x; 1.1453x over previous
//
#include <hip/hip_runtime.h>
#include <hip/hip_bf16.h>
#include <stdint.h>

typedef __hip_bfloat16 bf16;
typedef __bf16 bf16x8 __attribute__((ext_vector_type(8)));
typedef float f32x4 __attribute__((ext_vector_type(4)));

#define NB 1024
#define NM 4096
#define NZ 64
#define NH 8192

__device__ __forceinline__ float bf2f(bf16 x) { return __bfloat162float(x); }
__device__ __forceinline__ bf16 f2bf(float x) { return __float2bfloat16(x); }
__device__ __forceinline__ float sigf(float x) { return 1.f / (1.f + __expf(-x)); }

// fp32 x -> bf16 (4 elements/thread)
__global__ __launch_bounds__(256) void cvt_f32_bf16(const float* __restrict__ src,
                                                    bf16* __restrict__ dst, int n4) {
  const int i = blockIdx.x * 256 + threadIdx.x;
  if (i >= n4) return;
  const float4 v = ((const float4*)src)[i];
  bf16 o[4] = {f2bf(v.x), f2bf(v.y), f2bf(v.z), f2bf(v.w)};
  *(short4*)&dst[i * 4] = *(short4*)o;
}

__global__ void zero_f32(float* p, int n) {
  int i = blockIdx.x * blockDim.x + threadIdx.x;
  if (i < n) p[i] = 0.f;
}

#define VMW8 asm volatile("s_waitcnt vmcnt(8)" ::: "memory")
#define VMW0 asm volatile("s_waitcnt vmcnt(0)" ::: "memory")
#define LGKM0 asm volatile("s_waitcnt lgkmcnt(0)" ::: "memory")

// ---------------------------------------------------------------------------
// MFMA NT GEMM v4 (unchanged from r3): C[r,c] = relu(sum_k A[r,k]*W[c,k]+bias[c])
// At its structure's documented ceiling for this shape (~350 TF, m102 curve).
// ---------------------------------------------------------------------------
__global__ __launch_bounds__(256) void gemm_nt(const bf16* __restrict__ A,
                                               const float* __restrict__ W,
                                               const float* __restrict__ bias,
                                               bf16* __restrict__ C,
                                               int K, int N) {
  __shared__ __attribute__((aligned(16))) bf16 smA[3][128 * 64];  // 48 KB
  __shared__ __attribute__((aligned(16))) bf16 smB[2][64 * 64];   // 16 KB
  const int tid  = threadIdx.x;
  const int lane = tid & 63;
  const int w    = tid >> 6;   // 0..3
  const int wr   = w >> 1;     // 0..1 : 64-row group
  const int wc   = w & 1;      // 0..1 : 32-col group

  // XCD-bijective swizzle (hw linear id: x fastest, gridDim.x == 8)
  const int lid  = blockIdx.y * 8 + blockIdx.x;   // 0..511
  const int wgid = (lid & 7) * 64 + (lid >> 3);   // per-XCD contiguous chunk
  const int row0 = (wgid & 7) * 128;
  const int col0 = (wgid >> 3) * 64;

  f32x4 acc[4][2];
#pragma unroll
  for (int i = 0; i < 4; i++)
#pragma unroll
    for (int j = 0; j < 2; j++) acc[i][j] = (f32x4){0.f, 0.f, 0.f, 0.f};

  const int swr = tid >> 2;
  const int swk = (tid & 3) * 16;
  const float* wp = W + (size_t)(col0 + swr) * K + swk;
  const int swz = (swr & 7) << 3;   // element XOR for this row
  const int woff0 = swr * 64 + ((swk + 0) ^ swz);
  const int woff1 = swr * 64 + ((swk + 8) ^ swz);

  auto load_W = [&](float4 (&wv)[4], int kk) {
    wv[0] = *(const float4*)(wp + kk);
    wv[1] = *(const float4*)(wp + kk + 4);
    wv[2] = *(const float4*)(wp + kk + 8);
    wv[3] = *(const float4*)(wp + kk + 12);
  };

  auto stage_A = [&](int slot, int kk) {
#pragma unroll
    for (int q = 0; q < 4; q++) {
      const int chunk = q * 256 + w * 64 + lane;
      const int r  = chunk >> 3;
      const int ke = ((chunk & 7) ^ (r & 7)) * 8;
      __builtin_amdgcn_global_load_lds(
          (__attribute__((address_space(1))) unsigned int*)(A + (size_t)(row0 + r) * K + (kk + ke)),
          (__attribute__((address_space(3))) unsigned int*)(&smA[slot][(q * 256 + w * 64) * 8]),
          16, 0, 0);
    }
  };

  auto write_W = [&](int slot, const float4 (&wv)[4]) {
    bf16 t[16] = {f2bf(wv[0].x), f2bf(wv[0].y), f2bf(wv[0].z), f2bf(wv[0].w),
                  f2bf(wv[1].x), f2bf(wv[1].y), f2bf(wv[1].z), f2bf(wv[1].w),
                  f2bf(wv[2].x), f2bf(wv[2].y), f2bf(wv[2].z), f2bf(wv[2].w),
                  f2bf(wv[3].x), f2bf(wv[3].y), f2bf(wv[3].z), f2bf(wv[3].w)};
    *(bf16x8*)&smB[slot][woff0] = ((bf16x8*)t)[0];
    *(bf16x8*)&smB[slot][woff1] = ((bf16x8*)t)[1];
  };

  auto compute = [&](int sa, int ws) {
#pragma unroll
    for (int ks = 0; ks < 64; ks += 32) {
      const int kq = ks + (lane >> 4) * 8;   // frag: [m|n = lane&15][k = quad*8+j]
      bf16x8 af[4], bfr[2];
#pragma unroll
      for (int i = 0; i < 4; i++) {
        const int r = wr * 64 + i * 16 + (lane & 15);
        af[i] = *(const bf16x8*)&smA[sa][r * 64 + (kq ^ ((r & 7) << 3))];
      }
#pragma unroll
      for (int j = 0; j < 2; j++) {
        const int r = wc * 32 + j * 16 + (lane & 15);
        bfr[j] = *(const bf16x8*)&smB[ws][r * 64 + (kq ^ ((r & 7) << 3))];
      }
#pragma unroll
      for (int i = 0; i < 4; i++)
#pragma unroll
        for (int j = 0; j < 2; j++)
          acc[i][j] = __builtin_amdgcn_mfma_f32_16x16x32_bf16(af[i], bfr[j], acc[i][j], 0, 0, 0);
    }
  };

  const int K64 = K >> 6;   // 64 K-steps; even, >= 4
  float4 wA[4], wB[4];

  load_W(wA, 0);
  stage_A(0, 0);
  asm volatile("" ::: "memory");
  load_W(wB, 64);
  stage_A(1, 64);

  int sa = 0;
  for (int i = 0; i + 2 < K64; i += 2) {
    const int nx  = (sa + 1 == 3) ? 0 : sa + 1;
    const int nnx = (nx + 1 == 3) ? 0 : nx + 1;
    VMW8;
    write_W(0, wA);
    LGKM0;
    __builtin_amdgcn_s_barrier();
    __builtin_amdgcn_sched_barrier(0);
    load_W(wA, (i + 2) * 64);
    stage_A(nnx, (i + 2) * 64);
    compute(sa, 0);
    VMW8;
    write_W(1, wB);
    LGKM0;
    __builtin_amdgcn_s_barrier();
    __builtin_amdgcn_sched_barrier(0);
    load_W(wB, (i + 3) * 64);
    stage_A(sa, (i + 3) * 64);
    compute(nx, 1);
    sa = nnx;
  }
  VMW8;
  write_W(0, wA);
  LGKM0;
  __builtin_amdgcn_s_barrier();
  __builtin_amdgcn_sched_barrier(0);
  compute(sa, 0);
  VMW0;
  write_W(1, wB);
  LGKM0;
  __builtin_amdgcn_s_barrier();
  __builtin_amdgcn_sched_barrier(0);
  compute((sa + 1 == 3) ? 0 : sa + 1, 1);

  // C/D layout: col = lane&15, row = (lane>>4)*4 + t   [m89-verified]
#pragma unroll
  for (int i = 0; i < 4; i++) {
#pragma unroll
    for (int j = 0; j < 2; j++) {
      const int cc = col0 + wc * 32 + j * 16 + (lane & 15);
      const float bs = bias[cc];
#pragma unroll
      for (int t = 0; t < 4; t++) {
        const int rr = row0 + wr * 64 + i * 16 + (lane >> 4) * 4 + t;
        float v = acc[i][j][t] + bs;
        v = v > 0.f ? v : 0.f;   // relu (both encoder layers)
        C[(size_t)rr * N + cc] = f2bf(v);
      }
    }
  }
}

// ---------------------------------------------------------------------------
// mu/logvar split-K v3: zpre[b,0..63]=mu, [64..127]=lv (fp32 atomics).
// b-tile 32 -> grid (32,16) = 512 blocks = 2/CU (was 256 = 1/CU, latency-bound
// serial chunk chain). Inner sW read remapped tj*8+j -> 16*j+tj: banks now 16
// distinct per instr (was 4 distinct = 4-way conflict in v1/v2).
// ---------------------------------------------------------------------------
__global__ __launch_bounds__(256) void mulv_splitk(const bf16* __restrict__ h2,
                                                   const float* __restrict__ muw,
                                                   const float* __restrict__ lvw,
                                                   float* __restrict__ zpre) {
  __shared__ float sA[32][33];    // [k][b], pad -> conflict-free av reads
  __shared__ float sW[32][128];   // [k][j]
  const int tid = threadIdx.x;
  const int b0 = blockIdx.x * 32;
  const int k0 = blockIdx.y * 256;
  const int tj = tid & 15;        // j = 16*jj + tj (conflict-free)
  const int tb = tid >> 4;        // 0..15 : 2 b's each
  float acc[2][8];
#pragma unroll
  for (int i = 0; i < 2; i++)
#pragma unroll
    for (int j = 0; j < 8; j++) acc[i][j] = 0.f;

  const int lb = tid >> 3, lk = (tid & 7) * 4;    // h2 loader: 4 bf16 = 8B
  const int wj = tid >> 1, wk = (tid & 1) * 16;   // weight loader: 16 floats
  const float* wrow = (wj < 64) ? (muw + (size_t)wj * NM) : (lvw + (size_t)(wj - 64) * NM);

  for (int kc = 0; kc < 256; kc += 32) {
    __syncthreads();
    {
      const uint2 v = *(const uint2*)(h2 + (size_t)(b0 + lb) * NM + (k0 + kc + lk));
      sA[lk + 0][lb] = __uint_as_float(v.x << 16);
      sA[lk + 1][lb] = __uint_as_float(v.x & 0xffff0000u);
      sA[lk + 2][lb] = __uint_as_float(v.y << 16);
      sA[lk + 3][lb] = __uint_as_float(v.y & 0xffff0000u);
      const float* q = wrow + (k0 + kc + wk);
#pragma unroll
      for (int i = 0; i < 4; i++) {
        const float4 f = *(const float4*)(q + i * 4);
        sW[wk + i * 4 + 0][wj] = f.x;
        sW[wk + i * 4 + 1][wj] = f.y;
        sW[wk + i * 4 + 2][wj] = f.z;
        sW[wk + i * 4 + 3][wj] = f.w;
      }
    }
    __syncthreads();
#pragma unroll
    for (int k = 0; k < 32; k++) {
      const float av0 = sA[k][tb * 2 + 0];
      const float av1 = sA[k][tb * 2 + 1];
      float wv[8];
#pragma unroll
      for (int j = 0; j < 8; j++) wv[j] = sW[k][16 * j + tj];
#pragma unroll
      for (int j = 0; j < 8; j++) {
        acc[0][j] += av0 * wv[j];
        acc[1][j] += av1 * wv[j];
      }
    }
  }
#pragma unroll
  for (int i = 0; i < 2; i++)
#pragma unroll
    for (int j = 0; j < 8; j++)
      atomicAdd(&zpre[(size_t)(b0 + tb * 2 + i) * 128 + 16 * j + tj], acc[i][j]);
}

// mu/lv bias + reparameterization; fp32 outputs, fp32 z (ws)
__global__ void zfin(const float* __restrict__ zpre, const float* __restrict__ eps,
                     const float* __restrict__ mub, const float* __restrict__ lvb,
                     float* __restrict__ out_mu, float* __restrict__ out_lv,
                     float* __restrict__ z) {
  const int i = blockIdx.x * 256 + threadIdx.x;   // B*Z = 65536
  const int b = i >> 6, j = i & 63;
  const float mu = zpre[(size_t)b * 128 + j] + mub[j];
  const float lv = zpre[(size_t)b * 128 + 64 + j] + lvb[j];
  const float zz = mu + expf(0.5f * lv) * eps[i];
  out_mu[i] = mu;
  out_lv[i] = lv;
  z[i] = zz;
}

// ---------------------------------------------------------------------------
// Fused decoder branch v3: thread owns an m-PAIR (2 m) x 8 b -> per k, 3 LDS
// instrs (1xf4 fw + 2xf4 z) feed 32 FMA (was 5 instrs / 32 FMA): -40% LDS
// issue, the dominant pipe. Tail loads collapse to float4s covering both m's.
// Block = 64 b x 64 m; grid (16,16,4) = 1024 blocks (~3/CU). All fp32.
// ---------------------------------------------------------------------------
__global__ __launch_bounds__(256) void dec_fused(
    const float* __restrict__ z,
    const float* __restrict__ fw, const float* __restrict__ fb,
    const float* __restrict__ hw, const float* __restrict__ hb,
    const float* __restrict__ ow, const float* __restrict__ ob,
    float* __restrict__ out) {
  __shared__ __attribute__((aligned(16))) float sZ[64][68];   // [k][b]
  __shared__ __attribute__((aligned(16))) float sFW[64][132]; // [k][local fw row], 528B rows (16B-aligned)
  const int tid = threadIdx.x;
  const int b0 = blockIdx.x * 64;
  const int m0 = blockIdx.y * 256;
  const int mi = blockIdx.z;          // 0..3 : 64-m group
  {
    const int r  = tid >> 2;          // b-row 0..63
    const int c0 = (tid & 3) * 16;    // k-chunk
    const float* p = z + (size_t)(b0 + r) * NZ + c0;
#pragma unroll
    for (int i = 0; i < 16; i++) sZ[c0 + i][r] = p[i];
  }

  const int bq = tid >> 5;   // 0..7 : 8-batch group
  const int tm = tid & 31;   // 0..31 : m-pair index
  const int mb = m0 + mi * 64;

  {
    // stage fw rows [2*mb, 2*mb+128) x 64k, transposed: sFW[k][localrow]
    const int R0 = 2 * mb;
#pragma unroll
    for (int q = 0; q < 8; q++) {
      const int v = tid + q * 256;        // 0..2047 float4-ids
      const int grow = v >> 4;            // 0..127
      const int gk = (v & 15) * 4;
      const float4 f4 = *(const float4*)&fw[(size_t)(R0 + grow) * NZ + gk];
      sFW[gk + 0][grow] = f4.x;
      sFW[gk + 1][grow] = f4.y;
      sFW[gk + 2][grow] = f4.z;
      sFW[gk + 3][grow] = f4.w;
    }
  }
  __syncthreads();

  const int mA = mb + 2 * tm;   // even; thread covers m in {mA, mA+1}
  const float4 fb4 = *(const float4*)&fb[2 * mA];   // {A0,A1,B0,B1}, 16B-aligned
  float aA0[8], aA1[8], aB0[8], aB1[8];
#pragma unroll
  for (int j = 0; j < 8; j++) { aA0[j] = fb4.x; aA1[j] = fb4.y; aB0[j] = fb4.z; aB1[j] = fb4.w; }

#pragma unroll 8
  for (int k = 0; k < 64; k++) {
    const float4 w4 = *(const float4*)&sFW[k][4 * tm];   // fw rows {2mA,2mA+1,2mA+2,2mA+3}
    const float4 z0 = *(const float4*)&sZ[k][bq * 8 + 0];
    const float4 z1 = *(const float4*)&sZ[k][bq * 8 + 4];
    const float zv[8] = {z0.x, z0.y, z0.z, z0.w, z1.x, z1.y, z1.z, z1.w};
#pragma unroll
    for (int j = 0; j < 8; j++) {
      aA0[j] += zv[j] * w4.x;
      aA1[j] += zv[j] * w4.y;
      aB0[j] += zv[j] * w4.z;
      aB1[j] += zv[j] * w4.w;
    }
  }

  // tail: 2x2 sigmoid chain + output dot, both m's per thread
  float4 hwA[2], hwB[2], hb4[2];
#pragma unroll
  for (int l = 0; l < 2; l++) {
    hwA[l] = *(const float4*)&hw[((size_t)l * NM + mA) * 4];       // m=mA 2x2
    hwB[l] = *(const float4*)&hw[((size_t)l * NM + mA) * 4 + 4];   // m=mA+1 2x2
    hb4[l] = *(const float4*)&hb[(size_t)l * NH + 2 * mA];         // {A0,A1,B0,B1}
  }
  const float4 o4 = *(const float4*)&ow[2 * mA];    // {A0,A1,B0,B1}
  const float2 ob2 = *(const float2*)&ob[mA];
#pragma unroll
  for (int j = 0; j < 8; j++) {
    float a0 = sigf(aA0[j]), a1 = sigf(aA1[j]);
    float b0v = sigf(aB0[j]), b1v = sigf(aB1[j]);
#pragma unroll
    for (int l = 0; l < 2; l++) {
      const float nA0 = sigf(hwA[l].x * a0 + hwA[l].y * a1 + hb4[l].x);
      const float nA1 = sigf(hwA[l].z * a0 + hwA[l].w * a1 + hb4[l].y);
      const float nB0 = sigf(hwB[l].x * b0v + hwB[l].y * b1v + hb4[l].z);
      const float nB1 = sigf(hwB[l].z * b0v + hwB[l].w * b1v + hb4[l].w);
      a0 = nA0; a1 = nA1; b0v = nB0; b1v = nB1;
    }
    const float outA = a0 * o4.x + a1 * o4.y + ob2.x;
    const float outB = b0v * o4.z + b1v * o4.w + ob2.y;
    float2 o2; o2.x = outA; o2.y = outB;
    *(float2*)&out[(size_t)(b0 + bq * 8 + j) * NM + mA] = o2;
  }
}

extern "C" void kernel_launch(void* const* d_in, const int* in_sizes, int n_in,
                              void* d_out, int out_size, void* d_ws, size_t ws_size,
                              hipStream_t stream) {
  const float* x   = (const float*)d_in[0];
  const float* eps = (const float*)d_in[1];
  const float* e1w = (const float*)d_in[2];
  const float* e1b = (const float*)d_in[3];
  const float* e2w = (const float*)d_in[4];
  const float* e2b = (const float*)d_in[5];
  const float* muw = (const float*)d_in[6];
  const float* mub = (const float*)d_in[7];
  const float* lvw = (const float*)d_in[8];
  const float* lvb = (const float*)d_in[9];
  const float* mfw = (const float*)d_in[10];
  const float* mfb = (const float*)d_in[11];
  const float* mhw = (const float*)d_in[12];
  const float* mhb = (const float*)d_in[13];
  const float* mow = (const float*)d_in[14];
  const float* mob = (const float*)d_in[15];
  const float* cfw = (const float*)d_in[16];
  const float* cfb = (const float*)d_in[17];
  const float* chw = (const float*)d_in[18];
  const float* chb = (const float*)d_in[19];
  const float* cow = (const float*)d_in[20];
  const float* cob = (const float*)d_in[21];

  // d_out regions (fp32 elements): out_x [0,4M), out_lc [4M,8M), mu, lv.
  // bf16 intermediates overlay dead byte-ranges:
  //   h1 bf16 @ bytes [0,8M)      (dead after enc2; dec-mean overwrites)
  //   xb bf16 @ bytes [16M,24M)   (dead after enc1)
  //   h2 bf16 @ bytes [16M,24M)   (overwrites xb; dead after mulv; dec-cov overwrites)
  char* ob_ = (char*)d_out;
  float* out_x  = (float*)ob_;
  float* out_lc = (float*)(ob_ + (16u << 20));
  float* out_mu = out_x + (size_t)2 * NB * NM;
  float* out_lv = out_mu + (size_t)NB * NZ;
  bf16* h1 = (bf16*)ob_;
  bf16* xb = (bf16*)(ob_ + (16u << 20));
  bf16* h2 = xb;

  // ws: zpre fp32 512KB + z fp32 256KB = 768KB (round-4-proven budget)
  float* zpre = (float*)d_ws;
  float* z    = (float*)((char*)d_ws + (1u << 19));

  cvt_f32_bf16<<<dim3(4096), 256, 0, stream>>>(x, xb, NB * NM / 4);
  zero_f32<<<dim3(512), 256, 0, stream>>>(zpre, NB * 128);
  gemm_nt<<<dim3(8, 64), 256, 0, stream>>>(xb, e1w, e1b, h1, NM, NM);
  gemm_nt<<<dim3(8, 64), 256, 0, stream>>>(h1, e2w, e2b, h2, NM, NM);
  mulv_splitk<<<dim3(32, 16), 256, 0, stream>>>(h2, muw, lvw, zpre);
  zfin<<<dim3(256), 256, 0, stream>>>(zpre, eps, mub, lvb, out_mu, out_lv, z);
  dec_fused<<<dim3(16, 16, 4), 256, 0, stream>>>(z, mfw, mfb, mhw, mhb, mow, mob, out_x);
  dec_fused<<<dim3(16, 16, 4), 256, 0, stream>>>(z, cfw, cfb, chw, chb, cow, cob, out_lc);
}

// Round 8
// 426.428 us; speedup vs baseline: 1.4337x; 1.0322x over previous
//
#include <hip/hip_runtime.h>
#include <hip/hip_bf16.h>
#include <stdint.h>

typedef __hip_bfloat16 bf16;
typedef __bf16 bf16x8 __attribute__((ext_vector_type(8)));
typedef float f32x4 __attribute__((ext_vector_type(4)));

#define NB 1024
#define NM 4096
#define NZ 64
#define NH 8192

__device__ __forceinline__ float bf2f(bf16 x) { return __bfloat162float(x); }
__device__ __forceinline__ bf16 f2bf(float x) { return __float2bfloat16(x); }
__device__ __forceinline__ float sigf(float x) { return 1.f / (1.f + __expf(-x)); }

// fp32 x -> bf16 (4 elements/thread)
__global__ __launch_bounds__(256) void cvt_f32_bf16(const float* __restrict__ src,
                                                    bf16* __restrict__ dst, int n4) {
  const int i = blockIdx.x * 256 + threadIdx.x;
  if (i >= n4) return;
  const float4 v = ((const float4*)src)[i];
  bf16 o[4] = {f2bf(v.x), f2bf(v.y), f2bf(v.z), f2bf(v.w)};
  *(short4*)&dst[i * 4] = *(short4*)o;
}

__global__ void zero_f32(float* p, int n) {
  int i = blockIdx.x * blockDim.x + threadIdx.x;
  if (i < n) p[i] = 0.f;
}

#define VMW4 asm volatile("s_waitcnt vmcnt(4)" ::: "memory")
#define VMW0 asm volatile("s_waitcnt vmcnt(0)" ::: "memory")
#define LGKM0 asm volatile("s_waitcnt lgkmcnt(0)" ::: "memory")

// ---------------------------------------------------------------------------
// MFMA NT GEMM v5: C[r,c] = relu( sum_k A[r,k]*W[c,k] + bias[c] )
// v5 = v4's counted-vmcnt pipeline at 8 WAVES (512 thr), wave -> 32x32 C tile.
// Rationale: r1(naive) == r3(pipelined) within 1% -> limiter is cross-wave
// concurrency (2 waves/SIMD), not schedule. Same 64KB LDS -> 2 blocks/CU but
// 16 waves/CU = 4/SIMD (2x TLP). Per-wave VMEM = 4/K-step (2 W f4, 2 A
// gload_lds) -> vmcnt(4) drains exactly one tile, depth-2 prefetch.
// Slots: A mod-3, W mod-2 (same invariants as v4, on-device verified r6).
// ---------------------------------------------------------------------------
__global__ __launch_bounds__(512) void gemm_nt(const bf16* __restrict__ A,
                                               const float* __restrict__ W,
                                               const float* __restrict__ bias,
                                               bf16* __restrict__ C,
                                               int K, int N) {
  __shared__ __attribute__((aligned(16))) bf16 smA[3][128 * 64];  // 48 KB
  __shared__ __attribute__((aligned(16))) bf16 smB[2][64 * 64];   // 16 KB
  const int tid  = threadIdx.x;
  const int lane = tid & 63;
  const int w    = tid >> 6;   // 0..7
  const int wr   = w >> 1;     // 0..3 : 32-row group
  const int wc   = w & 1;      // 0..1 : 32-col group

  // XCD-bijective swizzle (hw linear id: x fastest, gridDim.x == 8)
  const int lid  = blockIdx.y * 8 + blockIdx.x;   // 0..511
  const int wgid = (lid & 7) * 64 + (lid >> 3);   // per-XCD contiguous chunk
  const int row0 = (wgid & 7) * 128;
  const int col0 = (wgid >> 3) * 64;

  f32x4 acc[2][2];
#pragma unroll
  for (int i = 0; i < 2; i++)
#pragma unroll
    for (int j = 0; j < 2; j++) acc[i][j] = (f32x4){0.f, 0.f, 0.f, 0.f};

  // W staging: thread -> smB row tid>>3, k elems [(tid&7)*8, +8)
  const int swr = tid >> 3;          // 0..63
  const int swk = (tid & 7) * 8;     // 0..56
  const float* wp = W + (size_t)(col0 + swr) * K + swk;
  const int woff = swr * 64 + (swk ^ ((swr & 7) << 3));

  auto load_W = [&](float4 (&wv)[2], int kk) {
    wv[0] = *(const float4*)(wp + kk);
    wv[1] = *(const float4*)(wp + kk + 4);
  };

  auto stage_A = [&](int slot, int kk) {
#pragma unroll
    for (int q = 0; q < 2; q++) {
      const int chunk = q * 512 + w * 64 + lane;   // 0..1023
      const int r  = chunk >> 3;                   // 0..127
      const int ke = ((chunk & 7) ^ (r & 7)) * 8;
      __builtin_amdgcn_global_load_lds(
          (__attribute__((address_space(1))) unsigned int*)(A + (size_t)(row0 + r) * K + (kk + ke)),
          (__attribute__((address_space(3))) unsigned int*)(&smA[slot][(q * 512 + w * 64) * 8]),
          16, 0, 0);
    }
  };

  auto write_W = [&](int slot, const float4 (&wv)[2]) {
    bf16 t[8] = {f2bf(wv[0].x), f2bf(wv[0].y), f2bf(wv[0].z), f2bf(wv[0].w),
                 f2bf(wv[1].x), f2bf(wv[1].y), f2bf(wv[1].z), f2bf(wv[1].w)};
    *(bf16x8*)&smB[slot][woff] = *(bf16x8*)t;
  };

  auto compute = [&](int sa, int ws) {
#pragma unroll
    for (int ks = 0; ks < 64; ks += 32) {
      const int kq = ks + (lane >> 4) * 8;   // frag: [m|n = lane&15][k = quad*8+j]
      bf16x8 af[2], bfr[2];
#pragma unroll
      for (int i = 0; i < 2; i++) {
        const int r = wr * 32 + i * 16 + (lane & 15);
        af[i] = *(const bf16x8*)&smA[sa][r * 64 + (kq ^ ((r & 7) << 3))];
      }
#pragma unroll
      for (int j = 0; j < 2; j++) {
        const int r = wc * 32 + j * 16 + (lane & 15);
        bfr[j] = *(const bf16x8*)&smB[ws][r * 64 + (kq ^ ((r & 7) << 3))];
      }
#pragma unroll
      for (int i = 0; i < 2; i++)
#pragma unroll
        for (int j = 0; j < 2; j++)
          acc[i][j] = __builtin_amdgcn_mfma_f32_16x16x32_bf16(af[i], bfr[j], acc[i][j], 0, 0, 0);
    }
  };

  const int K64 = K >> 6;   // 64 K-steps; even, >= 4
  float4 wA[2], wB[2];

  // prologue: tiles 0,1 in flight; fence pins FIFO order [W0,A0 | W1,A1]
  load_W(wA, 0);
  stage_A(0, 0);
  asm volatile("" ::: "memory");
  load_W(wB, 64);
  stage_A(1, 64);

  int sa = 0;   // slot of tile i (even body); tile t -> slot t%3
  for (int i = 0; i + 2 < K64; i += 2) {
    const int nx  = (sa + 1 == 3) ? 0 : sa + 1;
    const int nnx = (nx + 1 == 3) ? 0 : nx + 1;
    VMW4;                      // tile i drained; i+1 stays in flight
    write_W(0, wA);
    LGKM0;
    __builtin_amdgcn_s_barrier();
    __builtin_amdgcn_sched_barrier(0);
    load_W(wA, (i + 2) * 64);
    stage_A(nnx, (i + 2) * 64);
    compute(sa, 0);
    VMW4;
    write_W(1, wB);
    LGKM0;
    __builtin_amdgcn_s_barrier();
    __builtin_amdgcn_sched_barrier(0);
    load_W(wB, (i + 3) * 64);
    stage_A(sa, (i + 3) * 64);
    compute(nx, 1);
    sa = nnx;
  }
  // peel K64-2 (even, W slot 0)
  VMW4;
  write_W(0, wA);
  LGKM0;
  __builtin_amdgcn_s_barrier();
  __builtin_amdgcn_sched_barrier(0);
  compute(sa, 0);
  // peel K64-1 (odd, W slot 1)
  VMW0;
  write_W(1, wB);
  LGKM0;
  __builtin_amdgcn_s_barrier();
  __builtin_amdgcn_sched_barrier(0);
  compute((sa + 1 == 3) ? 0 : sa + 1, 1);

  // C/D layout: col = lane&15, row = (lane>>4)*4 + t   [m89-verified]
#pragma unroll
  for (int i = 0; i < 2; i++) {
#pragma unroll
    for (int j = 0; j < 2; j++) {
      const int cc = col0 + wc * 32 + j * 16 + (lane & 15);
      const float bs = bias[cc];
#pragma unroll
      for (int t = 0; t < 4; t++) {
        const int rr = row0 + wr * 32 + i * 16 + (lane >> 4) * 4 + t;
        float v = acc[i][j][t] + bs;
        v = v > 0.f ? v : 0.f;   // relu (both encoder layers)
        C[(size_t)rr * N + cc] = f2bf(v);
      }
    }
  }
}

// ---------------------------------------------------------------------------
// mu/logvar split-K v3 (unchanged from r6): zpre[b,0..63]=mu, [64..127]=lv.
// ---------------------------------------------------------------------------
__global__ __launch_bounds__(256) void mulv_splitk(const bf16* __restrict__ h2,
                                                   const float* __restrict__ muw,
                                                   const float* __restrict__ lvw,
                                                   float* __restrict__ zpre) {
  __shared__ float sA[32][33];    // [k][b], pad -> conflict-free av reads
  __shared__ float sW[32][128];   // [k][j]
  const int tid = threadIdx.x;
  const int b0 = blockIdx.x * 32;
  const int k0 = blockIdx.y * 256;
  const int tj = tid & 15;        // j = 16*jj + tj (conflict-free)
  const int tb = tid >> 4;        // 0..15 : 2 b's each
  float acc[2][8];
#pragma unroll
  for (int i = 0; i < 2; i++)
#pragma unroll
    for (int j = 0; j < 8; j++) acc[i][j] = 0.f;

  const int lb = tid >> 3, lk = (tid & 7) * 4;    // h2 loader: 4 bf16 = 8B
  const int wj = tid >> 1, wk = (tid & 1) * 16;   // weight loader: 16 floats
  const float* wrow = (wj < 64) ? (muw + (size_t)wj * NM) : (lvw + (size_t)(wj - 64) * NM);

  for (int kc = 0; kc < 256; kc += 32) {
    __syncthreads();
    {
      const uint2 v = *(const uint2*)(h2 + (size_t)(b0 + lb) * NM + (k0 + kc + lk));
      sA[lk + 0][lb] = __uint_as_float(v.x << 16);
      sA[lk + 1][lb] = __uint_as_float(v.x & 0xffff0000u);
      sA[lk + 2][lb] = __uint_as_float(v.y << 16);
      sA[lk + 3][lb] = __uint_as_float(v.y & 0xffff0000u);
      const float* q = wrow + (k0 + kc + wk);
#pragma unroll
      for (int i = 0; i < 4; i++) {
        const float4 f = *(const float4*)(q + i * 4);
        sW[wk + i * 4 + 0][wj] = f.x;
        sW[wk + i * 4 + 1][wj] = f.y;
        sW[wk + i * 4 + 2][wj] = f.z;
        sW[wk + i * 4 + 3][wj] = f.w;
      }
    }
    __syncthreads();
#pragma unroll
    for (int k = 0; k < 32; k++) {
      const float av0 = sA[k][tb * 2 + 0];
      const float av1 = sA[k][tb * 2 + 1];
      float wv[8];
#pragma unroll
      for (int j = 0; j < 8; j++) wv[j] = sW[k][16 * j + tj];
#pragma unroll
      for (int j = 0; j < 8; j++) {
        acc[0][j] += av0 * wv[j];
        acc[1][j] += av1 * wv[j];
      }
    }
  }
#pragma unroll
  for (int i = 0; i < 2; i++)
#pragma unroll
    for (int j = 0; j < 8; j++)
      atomicAdd(&zpre[(size_t)(b0 + tb * 2 + i) * 128 + 16 * j + tj], acc[i][j]);
}

// mu/lv bias + reparameterization; fp32 outputs, fp32 z (ws)
__global__ void zfin(const float* __restrict__ zpre, const float* __restrict__ eps,
                     const float* __restrict__ mub, const float* __restrict__ lvb,
                     float* __restrict__ out_mu, float* __restrict__ out_lv,
                     float* __restrict__ z) {
  const int i = blockIdx.x * 256 + threadIdx.x;   // B*Z = 65536
  const int b = i >> 6, j = i & 63;
  const float mu = zpre[(size_t)b * 128 + j] + mub[j];
  const float lv = zpre[(size_t)b * 128 + 64 + j] + lvb[j];
  const float zz = mu + expf(0.5f * lv) * eps[i];
  out_mu[i] = mu;
  out_lv[i] = lv;
  z[i] = zz;
}

// ---------------------------------------------------------------------------
// Fused decoder branch v4: fw staged in TWO k-halves (sFW[32][132] = 16.9KB,
// total LDS 34.3KB) -> 4 blocks/CU, full 1024-block residency (was 3/CU with
// a ragged 4th wave). Cost: one extra barrier pair. Else identical to v3
// (m-pair x 8b per thread, 3 LDS b128 feed 32 FMA per k).
// ---------------------------------------------------------------------------
__global__ __launch_bounds__(256) void dec_fused(
    const float* __restrict__ z,
    const float* __restrict__ fw, const float* __restrict__ fb,
    const float* __restrict__ hw, const float* __restrict__ hb,
    const float* __restrict__ ow, const float* __restrict__ ob,
    float* __restrict__ out) {
  __shared__ __attribute__((aligned(16))) float sZ[64][68];   // 17.4 KB
  __shared__ __attribute__((aligned(16))) float sFW[32][132]; // 16.9 KB
  const int tid = threadIdx.x;
  const int b0 = blockIdx.x * 64;
  const int m0 = blockIdx.y * 256;
  const int mi = blockIdx.z;          // 0..3 : 64-m group
  {
    const int r  = tid >> 2;          // b-row 0..63
    const int c0 = (tid & 3) * 16;    // k-chunk
    const float* p = z + (size_t)(b0 + r) * NZ + c0;
#pragma unroll
    for (int i = 0; i < 16; i++) sZ[c0 + i][r] = p[i];
  }

  const int bq = tid >> 5;   // 0..7 : 8-batch group
  const int tm = tid & 31;   // 0..31 : m-pair index
  const int mb = m0 + mi * 64;
  const int mA = mb + 2 * tm;   // even; thread covers m in {mA, mA+1}

  const float4 fb4 = *(const float4*)&fb[2 * mA];   // {A0,A1,B0,B1}
  float aA0[8], aA1[8], aB0[8], aB1[8];
#pragma unroll
  for (int j = 0; j < 8; j++) { aA0[j] = fb4.x; aA1[j] = fb4.y; aB0[j] = fb4.z; aB1[j] = fb4.w; }

  const int R0 = 2 * mb;
#pragma unroll
  for (int kh = 0; kh < 2; kh++) {
    __syncthreads();   // prev-half compute done (kh=0: harmless)
    {
      // stage fw rows [2*mb,+128) x k [kh*32,+32), transposed: sFW[k2][localrow]
#pragma unroll
      for (int q = 0; q < 4; q++) {
        const int v = tid + q * 256;        // 0..1023 float4-ids
        const int grow = v >> 3;            // 0..127
        const int gk = (v & 7) * 4;         // 0..28
        const float4 f4 = *(const float4*)&fw[(size_t)(R0 + grow) * NZ + kh * 32 + gk];
        sFW[gk + 0][grow] = f4.x;
        sFW[gk + 1][grow] = f4.y;
        sFW[gk + 2][grow] = f4.z;
        sFW[gk + 3][grow] = f4.w;
      }
    }
    __syncthreads();   // sFW half (and, at kh=0, sZ) visible

#pragma unroll 8
    for (int k2 = 0; k2 < 32; k2++) {
      const int k = kh * 32 + k2;
      const float4 w4 = *(const float4*)&sFW[k2][4 * tm];   // fw rows {2mA..2mA+3}
      const float4 z0 = *(const float4*)&sZ[k][bq * 8 + 0];
      const float4 z1 = *(const float4*)&sZ[k][bq * 8 + 4];
      const float zv[8] = {z0.x, z0.y, z0.z, z0.w, z1.x, z1.y, z1.z, z1.w};
#pragma unroll
      for (int j = 0; j < 8; j++) {
        aA0[j] += zv[j] * w4.x;
        aA1[j] += zv[j] * w4.y;
        aB0[j] += zv[j] * w4.z;
        aB1[j] += zv[j] * w4.w;
      }
    }
  }

  // tail: 2x2 sigmoid chain + output dot, both m's per thread
  float4 hwA[2], hwB[2], hb4[2];
#pragma unroll
  for (int l = 0; l < 2; l++) {
    hwA[l] = *(const float4*)&hw[((size_t)l * NM + mA) * 4];       // m=mA 2x2
    hwB[l] = *(const float4*)&hw[((size_t)l * NM + mA) * 4 + 4];   // m=mA+1 2x2
    hb4[l] = *(const float4*)&hb[(size_t)l * NH + 2 * mA];         // {A0,A1,B0,B1}
  }
  const float4 o4 = *(const float4*)&ow[2 * mA];    // {A0,A1,B0,B1}
  const float2 ob2 = *(const float2*)&ob[mA];
#pragma unroll
  for (int j = 0; j < 8; j++) {
    float a0 = sigf(aA0[j]), a1 = sigf(aA1[j]);
    float b0v = sigf(aB0[j]), b1v = sigf(aB1[j]);
#pragma unroll
    for (int l = 0; l < 2; l++) {
      const float nA0 = sigf(hwA[l].x * a0 + hwA[l].y * a1 + hb4[l].x);
      const float nA1 = sigf(hwA[l].z * a0 + hwA[l].w * a1 + hb4[l].y);
      const float nB0 = sigf(hwB[l].x * b0v + hwB[l].y * b1v + hb4[l].z);
      const float nB1 = sigf(hwB[l].z * b0v + hwB[l].w * b1v + hb4[l].w);
      a0 = nA0; a1 = nA1; b0v = nB0; b1v = nB1;
    }
    const float outA = a0 * o4.x + a1 * o4.y + ob2.x;
    const float outB = b0v * o4.z + b1v * o4.w + ob2.y;
    float2 o2; o2.x = outA; o2.y = outB;
    *(float2*)&out[(size_t)(b0 + bq * 8 + j) * NM + mA] = o2;
  }
}

extern "C" void kernel_launch(void* const* d_in, const int* in_sizes, int n_in,
                              void* d_out, int out_size, void* d_ws, size_t ws_size,
                              hipStream_t stream) {
  const float* x   = (const float*)d_in[0];
  const float* eps = (const float*)d_in[1];
  const float* e1w = (const float*)d_in[2];
  const float* e1b = (const float*)d_in[3];
  const float* e2w = (const float*)d_in[4];
  const float* e2b = (const float*)d_in[5];
  const float* muw = (const float*)d_in[6];
  const float* mub = (const float*)d_in[7];
  const float* lvw = (const float*)d_in[8];
  const float* lvb = (const float*)d_in[9];
  const float* mfw = (const float*)d_in[10];
  const float* mfb = (const float*)d_in[11];
  const float* mhw = (const float*)d_in[12];
  const float* mhb = (const float*)d_in[13];
  const float* mow = (const float*)d_in[14];
  const float* mob = (const float*)d_in[15];
  const float* cfw = (const float*)d_in[16];
  const float* cfb = (const float*)d_in[17];
  const float* chw = (const float*)d_in[18];
  const float* chb = (const float*)d_in[19];
  const float* cow = (const float*)d_in[20];
  const float* cob = (const float*)d_in[21];

  // d_out regions (fp32 elements): out_x [0,4M), out_lc [4M,8M), mu, lv.
  // bf16 intermediates overlay dead byte-ranges:
  //   h1 bf16 @ bytes [0,8M)      (dead after enc2; dec-mean overwrites)
  //   xb bf16 @ bytes [16M,24M)   (dead after enc1)
  //   h2 bf16 @ bytes [16M,24M)   (overwrites xb; dead after mulv; dec-cov overwrites)
  char* ob_ = (char*)d_out;
  float* out_x  = (float*)ob_;
  float* out_lc = (float*)(ob_ + (16u << 20));
  float* out_mu = out_x + (size_t)2 * NB * NM;
  float* out_lv = out_mu + (size_t)NB * NZ;
  bf16* h1 = (bf16*)ob_;
  bf16* xb = (bf16*)(ob_ + (16u << 20));
  bf16* h2 = xb;

  // ws: zpre fp32 512KB + z fp32 256KB = 768KB (round-4-proven budget)
  float* zpre = (float*)d_ws;
  float* z    = (float*)((char*)d_ws + (1u << 19));

  cvt_f32_bf16<<<dim3(4096), 256, 0, stream>>>(x, xb, NB * NM / 4);
  zero_f32<<<dim3(512), 256, 0, stream>>>(zpre, NB * 128);
  gemm_nt<<<dim3(8, 64), 512, 0, stream>>>(xb, e1w, e1b, h1, NM, NM);
  gemm_nt<<<dim3(8, 64), 512, 0, stream>>>(h1, e2w, e2b, h2, NM, NM);
  mulv_splitk<<<dim3(32, 16), 256, 0, stream>>>(h2, muw, lvw, zpre);
  zfin<<<dim3(256), 256, 0, stream>>>(zpre, eps, mub, lvb, out_mu, out_lv, z);
  dec_fused<<<dim3(16, 16, 4), 256, 0, stream>>>(z, mfw, mfb, mhw, mhb, mow, mob, out_x);
  dec_fused<<<dim3(16, 16, 4), 256, 0, stream>>>(z, cfw, cfb, chw, chb, cow, cob, out_lc);
}